// Round 1
// 474.956 us; speedup vs baseline: 1.0412x; 1.0412x over previous
//
#include <hip/hip_runtime.h>
#include <hip/hip_bf16.h>

// EncoderLayer: B=2,S=2048,D=1024,H=16,dk=dv=64,FF=4096
// r12: attention LDS-conflict round. rocprof showed SQ_LDS_BANK_CONFLICT=2.83e7
// (~45% of attn wall). (a) Vt: pad-72 scatter had 8-row stride 1152B = 0 mod
// 128B -> 4 banks; now unpadded [64][64] with 16B-chunk XOR swizzle
// ph = jq ^ (d&7) ^ ((d>>3)&7) -> write conflict-free, read balanced.
// (b) Pl: chunk swizzle ph = jq ^ (row>>2) -> stores 4-way -> ~2-way (free).
// (c) VALU: log2e/8 folded into Q at QKV-GEMM epilogue (exact: single fp32 mul
// before the only bf16 rounding) -> softmax is a bare v_exp_f32; P conversion
// via v_cvt_pk_bf16_f32 pairs (8 asm + 8 shifts vs 64 ops). ws unchanged.

#define D_MODEL 1024
#define SEQ 2048
#define MROWS 4096
#define LN_EPS 1e-5f

typedef __attribute__((ext_vector_type(8))) short s16x8;
typedef __attribute__((ext_vector_type(4))) float f32x4;

#define GLD_LDS16(g, l) __builtin_amdgcn_global_load_lds( \
    (const __attribute__((address_space(1))) void*)(g), \
    (__attribute__((address_space(3))) void*)(l), 16, 0, 0)

static __device__ __forceinline__ float bf2f(unsigned short u) {
    return __uint_as_float(((unsigned int)u) << 16);
}
static __device__ __forceinline__ unsigned short f2bf(float f) {
    unsigned int u = __float_as_uint(f);
    unsigned int r = (u + 0x7fffu + ((u >> 16) & 1u)) >> 16;
    return (unsigned short)r;
}
static __device__ __forceinline__ float h2f(unsigned short u) {
    union { unsigned short us; _Float16 h; } cv; cv.us = u; return (float)cv.h;
}
static __device__ __forceinline__ float ldx(const void* p, size_t i, int fl) {
    if (fl == 1) return ((const float*)p)[i];
    unsigned short u = ((const unsigned short*)p)[i];
    return (fl == 2) ? h2f(u) : bf2f(u);
}
static __device__ __forceinline__ void load4ext(const void* p, size_t idx, int fl, float o[4]) {
    if (fl == 1) {
        const float4 f = *reinterpret_cast<const float4*>((const float*)p + idx);
        o[0] = f.x; o[1] = f.y; o[2] = f.z; o[3] = f.w;
    } else {
        const ushort4 u = *reinterpret_cast<const ushort4*>((const unsigned short*)p + idx);
        if (fl == 2) { o[0]=h2f(u.x); o[1]=h2f(u.y); o[2]=h2f(u.z); o[3]=h2f(u.w); }
        else         { o[0]=bf2f(u.x); o[1]=bf2f(u.y); o[2]=bf2f(u.z); o[3]=bf2f(u.w); }
    }
}
static __device__ __forceinline__ void load4ws(const unsigned short* p, size_t idx, float o[4]) {
    const ushort4 u = *reinterpret_cast<const ushort4*>(p + idx);
    o[0] = bf2f(u.x); o[1] = bf2f(u.y); o[2] = bf2f(u.z); o[3] = bf2f(u.w);
}

// ---------- 3-way dtype detector on Wq ------------------------------------
__global__ void detect3_k(const unsigned short* __restrict__ w, int* __restrict__ flag) {
    const int t = threadIdx.x;
    float mbf = 0.f, mf16 = 0.f;
    for (int i = t; i < 512; i += 64) {
        float a = fabsf(bf2f(w[i])); if (!(a < 1e30f)) a = 1e30f; mbf = fmaxf(mbf, a);
        float b = fabsf(h2f(w[i]));  if (!(b < 1e30f)) b = 1e30f; mf16 = fmaxf(mf16, b);
    }
    #pragma unroll
    for (int off = 1; off < 64; off <<= 1) {
        mbf  = fmaxf(mbf,  __shfl_xor(mbf,  off));
        mf16 = fmaxf(mf16, __shfl_xor(mf16, off));
    }
    if (t == 0) {
        int f;
        if (mbf > 0.5f)       f = 1;   // fp32
        else if (mf16 > 0.5f) f = 0;   // bf16
        else                  f = 2;   // fp16
        *flag = f;
    }
}

// ---------- X (ext, [4096x1024]) -> bf16 ws -------------------------------
__global__ __launch_bounds__(256)
void cvtx_k(const void* __restrict__ X, unsigned short* __restrict__ out,
            const int* __restrict__ flagp) {
    const int fl = *flagp;
    const size_t idx = (size_t)blockIdx.x * 1024 + threadIdx.x * 4;
    float v[4];
    load4ext(X, idx, fl, v);
    ushort4 o = { f2bf(v[0]), f2bf(v[1]), f2bf(v[2]), f2bf(v[3]) };
    *reinterpret_cast<ushort4*>(out + idx) = o;
}

// ---------- W [K,N] ext -> WT bf16 [N,K] (64x64 tiles via LDS) -------------
__global__ __launch_bounds__(256)
void trans_k(const void* __restrict__ W, unsigned short* __restrict__ WT,
             int K, int N, const int* __restrict__ flagp) {
    const int fl = *flagp;
    __shared__ float Tf[64][65];
    const int tid = threadIdx.x;
    const int r0 = blockIdx.y * 64, c0 = blockIdx.x * 64;
    #pragma unroll
    for (int it = 0; it < 4; ++it) {
        int rr = (tid >> 4) + it * 16;
        float v[4];
        load4ext(W, (size_t)(r0 + rr) * N + c0 + (tid & 15) * 4, fl, v);
        Tf[rr][(tid & 15) * 4 + 0] = v[0];
        Tf[rr][(tid & 15) * 4 + 1] = v[1];
        Tf[rr][(tid & 15) * 4 + 2] = v[2];
        Tf[rr][(tid & 15) * 4 + 3] = v[3];
    }
    __syncthreads();
    #pragma unroll
    for (int it = 0; it < 4; ++it) {
        int nr = (tid >> 4) + it * 16;
        int kk = (tid & 15) * 4;
        ushort4 o = { f2bf(Tf[kk+0][nr]), f2bf(Tf[kk+1][nr]),
                      f2bf(Tf[kk+2][nr]), f2bf(Tf[kk+3][nr]) };
        *reinterpret_cast<ushort4*>(WT + (size_t)(c0 + nr) * K + r0 + kk) = o;
    }
}

// ---------- MFMA GEMM: out[M,N](bf16 ws) = A[M,K](bf16 ws) @ WT[N,K]^T -----
template<int RES, bool GELU, int BJ, bool FUSE3>
__global__ __launch_bounds__(256)
void gemm_mfma(const unsigned short* __restrict__ A,
               const unsigned short* __restrict__ WT,
               const void* __restrict__ b0, const void* __restrict__ b1,
               const void* __restrict__ b2, const void* __restrict__ res_,
               unsigned short* __restrict__ out, int M, int N, int K,
               const int* __restrict__ flagp)
{
    const int fl = *flagp;
    __shared__ unsigned short AsU[128 * 32];
    __shared__ unsigned short BsU[32 * BJ * 32];
    const int tid  = threadIdx.x;
    const int lane = tid & 63, wave = tid >> 6;
    const int lm = lane & 15, quad = lane >> 4;
    const int wr = wave >> 1, wc = wave & 1;
    const int rowBase = blockIdx.y * 128, colBase = blockIdx.x * (32 * BJ);

    f32x4 acc[4][BJ] = {};

    for (int k0 = 0; k0 < K; k0 += 32) {
        #pragma unroll
        for (int i = 0; i < 2; ++i) {
            int c = tid + 256 * i;
            GLD_LDS16(A  + ((size_t)(rowBase + (c >> 2)) * K + k0 + (c & 3) * 8), &AsU[c * 8]);
        }
        #pragma unroll
        for (int i = 0; i < BJ / 2; ++i) {
            int c = tid + 256 * i;
            GLD_LDS16(WT + ((size_t)(colBase + (c >> 2)) * K + k0 + (c & 3) * 8), &BsU[c * 8]);
        }
        __syncthreads();
        s16x8 a[4], b[BJ];
        #pragma unroll
        for (int i = 0; i < 4; ++i)
            a[i] = *reinterpret_cast<const s16x8*>(&AsU[(wr*64 + i*16 + lm) * 32 + quad*8]);
        #pragma unroll
        for (int j = 0; j < BJ; ++j)
            b[j] = *reinterpret_cast<const s16x8*>(&BsU[(wc*16*BJ + j*16 + lm) * 32 + quad*8]);
        #pragma unroll
        for (int i = 0; i < 4; ++i)
            #pragma unroll
            for (int j = 0; j < BJ; ++j)
                acc[i][j] = __builtin_amdgcn_mfma_f32_16x16x32_bf16(a[i], b[j], acc[i][j], 0, 0, 0);
        __syncthreads();
    }

    #pragma unroll
    for (int j = 0; j < BJ; ++j) {
        const int col = colBase + wc*16*BJ + j*16 + lm;
        const void* bp = b0;
        int bcol = col;
        if (FUSE3) {
            const int sel = col >> 10;
            bp = (sel == 0) ? b0 : ((sel == 1) ? b1 : b2);
            bcol = col & 1023;
        }
        const float bv = ldx(bp, (size_t)bcol, fl);
        #pragma unroll
        for (int i = 0; i < 4; ++i) {
            const int row0 = rowBase + wr*64 + i*16 + quad*4;
            #pragma unroll
            for (int r = 0; r < 4; ++r) {
                const int row = row0 + r;
                float v = acc[i][j][r] + bv;
                // fold softmax scale log2(e)/8 into Q (cols 0..1023 of fused
                // QKV). Single fp32 mul before the only bf16 rounding: exact.
                if (FUSE3) { if ((col >> 10) == 0) v *= 0.18033688011112042f; }
                if (RES == 1) v += ldx(res_, (size_t)row * N + col, fl);
                else if (RES == 2) v += bf2f(((const unsigned short*)res_)[(size_t)row * N + col]);
                if (GELU) v = 0.5f * v * (1.0f + erff(v * 0.70710678118654752f));
                out[(size_t)row * N + col] = f2bf(v);
            }
        }
    }
}

// ---------------- MFMA flash attention (r12) --------------------------------
// grid (SEQ/128, B*H), block 512 = 8 waves x 16 Q-rows. K-chunk = 64 keys.
// Fixed-max softmax with log2e/8 pre-folded into Q: p = exp2(s) directly.
// Vt: [64][64] 16B-chunk XOR swizzle (jq ^ (d&7) ^ ((d>>3)&7)) -> scatter
// writes hit all 32 banks (2 lanes/bank same-word = free). Pl: chunk swizzle
// jq ^ (row>>2) -> stores ~2-way. P f32->bf16 via v_cvt_pk_bf16_f32 pairs.
__global__ __launch_bounds__(512)
void attn_mfma(const unsigned short* __restrict__ Q, const unsigned short* __restrict__ Kb,
               const unsigned short* __restrict__ Vb, unsigned short* __restrict__ ctx,
               int ld)
{
    __shared__ unsigned short Ks[4096];     // [ks][key][32] linear (GLD dest)
    __shared__ unsigned short Vt[64 * 64];  // [d][key], swizzled 16B chunks
    __shared__ unsigned short Pl[8 * 1024]; // per-wave [ks][row16][32], swizzled

    const int tid = threadIdx.x;
    const int lane = tid & 63, wave = tid >> 6;
    const int lm = lane & 15, quad = lane >> 4;
    const int q0 = blockIdx.x * 128;
    const int bh = blockIdx.y;
    const int b = bh >> 4, h = bh & 15;
    const size_t base  = ((size_t)b * SEQ) * ld + (size_t)h * 64;
    const size_t cbase = ((size_t)b * SEQ) * D_MODEL + (size_t)h * 64;
    const int pbase = wave * 1024;
    const int qrow = q0 + wave * 16 + lm;

    s16x8 qf[2];
    #pragma unroll
    for (int ks = 0; ks < 2; ++ks)
        qf[ks] = *reinterpret_cast<const s16x8*>(
            Q + base + (size_t)qrow * ld + ks*32 + quad*8);

    f32x4 O[4] = {};
    float lpart[4] = { 0.f, 0.f, 0.f, 0.f };

    for (int j0 = 0; j0 < SEQ; j0 += 64) {
        __syncthreads();   // all waves done reading Ks/Vt before restage
        {   // stage K: one global_load_lds per thread (512 x 16B = 8KB)
            const int c = tid;
            GLD_LDS16(Kb + base + (size_t)(j0 + ((c >> 2) & 63)) * ld
                                + (c >> 8) * 32 + (c & 3) * 8, &Ks[c * 8]);
        }
        {   // stage V transposed, swizzled: 8 shorts per thread
            const int j = tid >> 3, dp = (tid & 7) * 8, jq = tid >> 6;
            s16x8 v = *reinterpret_cast<const s16x8*>(Vb + base + (size_t)(j0 + j) * ld + dp);
            #pragma unroll
            for (int i = 0; i < 8; ++i) {
                const int d = dp + i;
                const int ph = (jq ^ (d & 7) ^ ((d >> 3) & 7)) & 7;
                Vt[d * 64 + ph * 8 + (j & 7)] = (unsigned short)v[i];
            }
        }
        __syncthreads();

        // S = Q K^T (C-layout: row=quad*4+r, col=nt*16+lm)
        f32x4 s[4] = {};
        #pragma unroll
        for (int ks = 0; ks < 2; ++ks) {
            s16x8 bk[4];
            #pragma unroll
            for (int nt = 0; nt < 4; ++nt)
                bk[nt] = *reinterpret_cast<const s16x8*>(&Ks[ks*2048 + (nt*16 + lm)*32 + quad*8]);
            #pragma unroll
            for (int nt = 0; nt < 4; ++nt)
                s[nt] = __builtin_amdgcn_mfma_f32_16x16x32_bf16(qf[ks], bk[nt], s[nt], 0, 0, 0);
        }

        // fixed-max softmax: p = 2^s (scale folded into Q); pack pairs and
        // store to swizzled Pl; accumulate l per lane.
        #pragma unroll
        for (int nt = 0; nt < 4; ++nt) {
            const int jq = (nt & 1) * 2 + (lm >> 3);
            const int ph = (jq ^ quad) & 3;
            const int colp = pbase + (nt >> 1) * 512 + ph * 8 + (lm & 7);
            #pragma unroll
            for (int rp = 0; rp < 2; ++rp) {
                float p0 = __builtin_amdgcn_exp2f(s[nt][2*rp]);
                float p1 = __builtin_amdgcn_exp2f(s[nt][2*rp + 1]);
                lpart[2*rp]     += p0;
                lpart[2*rp + 1] += p1;
                unsigned int pk;
                asm("v_cvt_pk_bf16_f32 %0, %1, %2" : "=v"(pk) : "v"(p0), "v"(p1));
                const int row0 = quad * 4 + 2 * rp;
                Pl[colp + row0 * 32]       = (unsigned short)pk;
                Pl[colp + (row0 + 1) * 32] = (unsigned short)(pk >> 16);
            }
        }
        // same-wave LDS ordering: no barrier needed between P store and read

        // O += P V
        #pragma unroll
        for (int ks = 0; ks < 2; ++ks) {
            s16x8 pa = *reinterpret_cast<const s16x8*>(
                &Pl[pbase + ks*512 + lm*32 + ((quad ^ (lm >> 2)) & 3) * 8]);
            s16x8 vb[4];
            #pragma unroll
            for (int nt = 0; nt < 4; ++nt) {
                const int d = nt*16 + lm;
                const int ph = ((ks*4 + quad) ^ (d & 7) ^ ((d >> 3) & 7)) & 7;
                vb[nt] = *reinterpret_cast<const s16x8*>(&Vt[d * 64 + ph * 8]);
            }
            #pragma unroll
            for (int nt = 0; nt < 4; ++nt)
                O[nt] = __builtin_amdgcn_mfma_f32_16x16x32_bf16(pa, vb[nt], O[nt], 0, 0, 0);
        }
    }

    // epilogue: reduce l across the 16-lane row group once; O /= l; write ctx
    #pragma unroll
    for (int r = 0; r < 4; ++r) {
        float l = lpart[r];
        l += __shfl_xor(l, 1);
        l += __shfl_xor(l, 2);
        l += __shfl_xor(l, 4);
        l += __shfl_xor(l, 8);
        const float linv = 1.0f / l;
        const size_t ob = cbase + (size_t)(q0 + wave*16 + quad*4 + r) * D_MODEL;
        #pragma unroll
        for (int nt = 0; nt < 4; ++nt)
            ctx[ob + nt*16 + lm] = f2bf(O[nt][r] * linv);
    }
}

// ---------------- LayerNorm over rows of 1024 (bf16 in) ---------------------
template<bool OUTF32>
__global__ __launch_bounds__(256)
void ln_k(const unsigned short* __restrict__ X, const void* __restrict__ g,
          const void* __restrict__ b, void* __restrict__ out,
          const int* __restrict__ flagp)
{
    const int fl = *flagp;
    const int row = blockIdx.x, tid = threadIdx.x;
    float x[4];
    load4ws(X, (size_t)row * D_MODEL + tid*4, x);
    float s  = x[0] + x[1] + x[2] + x[3];
    float sq = fmaf(x[0],x[0], fmaf(x[1],x[1], fmaf(x[2],x[2], x[3]*x[3])));
    #pragma unroll
    for (int off = 1; off < 64; off <<= 1) {
        s  += __shfl_xor(s,  off);
        sq += __shfl_xor(sq, off);
    }
    __shared__ float red[8];
    const int wid = tid >> 6;
    if ((tid & 63) == 0) { red[wid] = s; red[4+wid] = sq; }
    __syncthreads();
    s  = red[0] + red[1] + red[2] + red[3];
    sq = red[4] + red[5] + red[6] + red[7];
    const float mean = s * (1.0f/1024.0f);
    const float var  = sq * (1.0f/1024.0f) - mean*mean;
    const float rstd = rsqrtf(var + LN_EPS);
    float gx[4], bx[4];
    load4ext(g, (size_t)tid*4, fl, gx);
    load4ext(b, (size_t)tid*4, fl, bx);
    float y[4];
    #pragma unroll
    for (int j = 0; j < 4; ++j) y[j] = (x[j] - mean) * rstd * gx[j] + bx[j];
    if (OUTF32) {
        float4 o4 = { y[0], y[1], y[2], y[3] };
        *reinterpret_cast<float4*>((float*)out + (size_t)row * D_MODEL + tid*4) = o4;
    } else {
        ushort4 o4 = { f2bf(y[0]), f2bf(y[1]), f2bf(y[2]), f2bf(y[3]) };
        *reinterpret_cast<ushort4*>((unsigned short*)out + (size_t)row * D_MODEL + tid*4) = o4;
    }
}

extern "C" void kernel_launch(void* const* d_in, const int* in_sizes, int n_in,
                              void* d_out, int out_size, void* d_ws, size_t ws_size,
                              hipStream_t stream) {
    const void* X  = d_in[0];
    const void* Wq = d_in[2];  const void* bq  = d_in[3];
    const void* Wk = d_in[4];  const void* bk  = d_in[5];
    const void* Wv = d_in[6];  const void* bv  = d_in[7];
    const void* Wo = d_in[8];  const void* bo  = d_in[9];
    const void* g1 = d_in[10]; const void* b1  = d_in[11];
    const void* W1 = d_in[12]; const void* bf1 = d_in[13];
    const void* W2 = d_in[14]; const void* bf2 = d_in[15];
    const void* g2 = d_in[16]; const void* b2  = d_in[17];

    int* flag = (int*)d_ws;
    unsigned short* base = (unsigned short*)((char*)d_ws + 4096);
    unsigned short* WTq  = base;                   // [1024,1024] } contiguous =
    unsigned short* WTk  = base + 1048576;         // [1024,1024] } WTqkv
    unsigned short* WTv  = base + 2097152;         // [1024,1024] } [3072,1024]
    unsigned short* WTo  = base + 3145728;         // [1024,1024]
    unsigned short* WT1  = base + 4194304;         // [4096,1024]
    unsigned short* WT2  = base + 8388608;         // [1024,4096]
    unsigned short* Xb   = base + 12582912;        // [4096,1024]
    unsigned short* Bqkv = base + 16777216;        // [4096,3072]
    unsigned short* Bctx = base + 29360128;        // [4096,1024]
    unsigned short* AO   = Bqkv;                   // attn_out [4096,1024] reuse
    unsigned short* H    = base + 33554432;        // [4096,4096]

    dim3 blk(256);
    detect3_k<<<1, 64, 0, stream>>>((const unsigned short*)Wq, flag);

    cvtx_k<<<dim3(4096), blk, 0, stream>>>(X, Xb, flag);
    trans_k<<<dim3(16,16), blk, 0, stream>>>(Wq, WTq, 1024, 1024, flag);
    trans_k<<<dim3(16,16), blk, 0, stream>>>(Wk, WTk, 1024, 1024, flag);
    trans_k<<<dim3(16,16), blk, 0, stream>>>(Wv, WTv, 1024, 1024, flag);
    trans_k<<<dim3(16,16), blk, 0, stream>>>(Wo, WTo, 1024, 1024, flag);
    trans_k<<<dim3(64,16), blk, 0, stream>>>(W1, WT1, 1024, 4096, flag);
    trans_k<<<dim3(16,64), blk, 0, stream>>>(W2, WT2, 4096, 1024, flag);

    // fused QKV: [4096,3072] = Xb @ WTqkv^T (768 blocks = 3/CU); Q pre-scaled
    gemm_mfma<0,false,4,true><<<dim3(24,32), blk, 0, stream>>>(
        Xb, WTq, bq, bk, bv, nullptr, Bqkv, MROWS, 3072, 1024, flag);

    // attention on strided QKV (ld=3072); block=512
    attn_mfma<<<dim3(SEQ/128, 32), dim3(512), 0, stream>>>(
        Bqkv, Bqkv + 1024, Bqkv + 2048, Bctx, 3072);

    // Wo proj + residual(X) -> Xb (pre-LN1), 128x64 tiles (512 blocks)
    gemm_mfma<1,false,2,false><<<dim3(16,32), blk, 0, stream>>>(
        Bctx, WTo, bo, nullptr, nullptr, X, Xb, MROWS, 1024, 1024, flag);
    // LN1 -> AO (attn_out; Bqkv reused)
    ln_k<false><<<dim3(4096), blk, 0, stream>>>(Xb, g1, b1, AO, flag);

    // FFN1 + gelu: full [4096,4096] (1024 blocks = 4/CU)
    gemm_mfma<0,true,4,false><<<dim3(32,32), blk, 0, stream>>>(
        AO, WT1, bf1, nullptr, nullptr, nullptr, H, MROWS, 4096, 1024, flag);
    // FFN2 + residual(AO) in-place, 128x64 tiles (512 blocks)
    gemm_mfma<2,false,2,false><<<dim3(16,32), blk, 0, stream>>>(
        H, WT2, bf2, nullptr, nullptr, AO, AO, MROWS, 1024, 4096, flag);

    // final LN -> fp32 d_out
    ln_k<true><<<dim3(4096), blk, 0, stream>>>(AO, g2, b2, d_out, flag);
}

// Round 2
// 466.536 us; speedup vs baseline: 1.0600x; 1.0180x over previous
//
#include <hip/hip_runtime.h>
#include <hip/hip_bf16.h>

// EncoderLayer: B=2,S=2048,D=1024,H=16,dk=dv=64,FF=4096
// r13: GEMM epilogue round. rocprof: FFN1 gemm 90us, MfmaUtil 15.5%, VALUBusy
// 38% -> epilogue-VALU-bound (libm erff ~50 ops x 64 elems/thread).
// (a) GELU via A&S 7.1.26 erf (|eps|<=1.5e-7, ~14 ops: rcp+exp2+5fma).
// (b) all GEMM epilogues: bf16 pack via v_cvt_pk_bf16_f32 pairs (RNE, same
//     rounding as manual f2bf). (c) T1 XCD swizzle in gemm_mfma (grids 768/
//     1024/512 all %8==0): contiguous tile chunk per XCD -> A/B panel L2 reuse
//     (FETCH 41MB -> ~28MB expected). Attention (r12 swizzles) unchanged.

#define D_MODEL 1024
#define SEQ 2048
#define MROWS 4096
#define LN_EPS 1e-5f

typedef __attribute__((ext_vector_type(8))) short s16x8;
typedef __attribute__((ext_vector_type(4))) float f32x4;

#define GLD_LDS16(g, l) __builtin_amdgcn_global_load_lds( \
    (const __attribute__((address_space(1))) void*)(g), \
    (__attribute__((address_space(3))) void*)(l), 16, 0, 0)

static __device__ __forceinline__ float bf2f(unsigned short u) {
    return __uint_as_float(((unsigned int)u) << 16);
}
static __device__ __forceinline__ unsigned short f2bf(float f) {
    unsigned int u = __float_as_uint(f);
    unsigned int r = (u + 0x7fffu + ((u >> 16) & 1u)) >> 16;
    return (unsigned short)r;
}
static __device__ __forceinline__ float h2f(unsigned short u) {
    union { unsigned short us; _Float16 h; } cv; cv.us = u; return (float)cv.h;
}
static __device__ __forceinline__ float ldx(const void* p, size_t i, int fl) {
    if (fl == 1) return ((const float*)p)[i];
    unsigned short u = ((const unsigned short*)p)[i];
    return (fl == 2) ? h2f(u) : bf2f(u);
}
static __device__ __forceinline__ void load4ext(const void* p, size_t idx, int fl, float o[4]) {
    if (fl == 1) {
        const float4 f = *reinterpret_cast<const float4*>((const float*)p + idx);
        o[0] = f.x; o[1] = f.y; o[2] = f.z; o[3] = f.w;
    } else {
        const ushort4 u = *reinterpret_cast<const ushort4*>((const unsigned short*)p + idx);
        if (fl == 2) { o[0]=h2f(u.x); o[1]=h2f(u.y); o[2]=h2f(u.z); o[3]=h2f(u.w); }
        else         { o[0]=bf2f(u.x); o[1]=bf2f(u.y); o[2]=bf2f(u.z); o[3]=bf2f(u.w); }
    }
}
static __device__ __forceinline__ void load4ws(const unsigned short* p, size_t idx, float o[4]) {
    const ushort4 u = *reinterpret_cast<const ushort4*>(p + idx);
    o[0] = bf2f(u.x); o[1] = bf2f(u.y); o[2] = bf2f(u.z); o[3] = bf2f(u.w);
}

// Fast exact-precision GELU: A&S 7.1.26 erf, |eps| <= 1.5e-7 (<< bf16 ulp).
static __device__ __forceinline__ float gelu_f(float v) {
    const float x  = v * 0.70710678118654752f;
    const float ax = fabsf(x);
    const float t  = __builtin_amdgcn_rcpf(fmaf(0.3275911f, ax, 1.0f));
    const float e  = __builtin_amdgcn_exp2f(-x * x * 1.4426950408889634f);
    float p = fmaf(1.061405429f, t, -1.453152027f);
    p = fmaf(p, t, 1.421413741f);
    p = fmaf(p, t, -0.284496736f);
    p = fmaf(p, t, 0.254829592f);
    p = p * t;
    float er = fmaf(-p, e, 1.0f);          // erf(|x|)
    er = copysignf(er, x);
    return 0.5f * v * (1.0f + er);
}

// ---------- 3-way dtype detector on Wq ------------------------------------
__global__ void detect3_k(const unsigned short* __restrict__ w, int* __restrict__ flag) {
    const int t = threadIdx.x;
    float mbf = 0.f, mf16 = 0.f;
    for (int i = t; i < 512; i += 64) {
        float a = fabsf(bf2f(w[i])); if (!(a < 1e30f)) a = 1e30f; mbf = fmaxf(mbf, a);
        float b = fabsf(h2f(w[i]));  if (!(b < 1e30f)) b = 1e30f; mf16 = fmaxf(mf16, b);
    }
    #pragma unroll
    for (int off = 1; off < 64; off <<= 1) {
        mbf  = fmaxf(mbf,  __shfl_xor(mbf,  off));
        mf16 = fmaxf(mf16, __shfl_xor(mf16, off));
    }
    if (t == 0) {
        int f;
        if (mbf > 0.5f)       f = 1;   // fp32
        else if (mf16 > 0.5f) f = 0;   // bf16
        else                  f = 2;   // fp16
        *flag = f;
    }
}

// ---------- X (ext, [4096x1024]) -> bf16 ws -------------------------------
__global__ __launch_bounds__(256)
void cvtx_k(const void* __restrict__ X, unsigned short* __restrict__ out,
            const int* __restrict__ flagp) {
    const int fl = *flagp;
    const size_t idx = (size_t)blockIdx.x * 1024 + threadIdx.x * 4;
    float v[4];
    load4ext(X, idx, fl, v);
    ushort4 o = { f2bf(v[0]), f2bf(v[1]), f2bf(v[2]), f2bf(v[3]) };
    *reinterpret_cast<ushort4*>(out + idx) = o;
}

// ---------- W [K,N] ext -> WT bf16 [N,K] (64x64 tiles via LDS) -------------
__global__ __launch_bounds__(256)
void trans_k(const void* __restrict__ W, unsigned short* __restrict__ WT,
             int K, int N, const int* __restrict__ flagp) {
    const int fl = *flagp;
    __shared__ float Tf[64][65];
    const int tid = threadIdx.x;
    const int r0 = blockIdx.y * 64, c0 = blockIdx.x * 64;
    #pragma unroll
    for (int it = 0; it < 4; ++it) {
        int rr = (tid >> 4) + it * 16;
        float v[4];
        load4ext(W, (size_t)(r0 + rr) * N + c0 + (tid & 15) * 4, fl, v);
        Tf[rr][(tid & 15) * 4 + 0] = v[0];
        Tf[rr][(tid & 15) * 4 + 1] = v[1];
        Tf[rr][(tid & 15) * 4 + 2] = v[2];
        Tf[rr][(tid & 15) * 4 + 3] = v[3];
    }
    __syncthreads();
    #pragma unroll
    for (int it = 0; it < 4; ++it) {
        int nr = (tid >> 4) + it * 16;
        int kk = (tid & 15) * 4;
        ushort4 o = { f2bf(Tf[kk+0][nr]), f2bf(Tf[kk+1][nr]),
                      f2bf(Tf[kk+2][nr]), f2bf(Tf[kk+3][nr]) };
        *reinterpret_cast<ushort4*>(WT + (size_t)(c0 + nr) * K + r0 + kk) = o;
    }
}

// ---------- MFMA GEMM: out[M,N](bf16 ws) = A[M,K](bf16 ws) @ WT[N,K]^T -----
template<int RES, bool GELU, int BJ, bool FUSE3>
__global__ __launch_bounds__(256)
void gemm_mfma(const unsigned short* __restrict__ A,
               const unsigned short* __restrict__ WT,
               const void* __restrict__ b0, const void* __restrict__ b1,
               const void* __restrict__ b2, const void* __restrict__ res_,
               unsigned short* __restrict__ out, int M, int N, int K,
               const int* __restrict__ flagp)
{
    const int fl = *flagp;
    __shared__ unsigned short AsU[128 * 32];
    __shared__ unsigned short BsU[32 * BJ * 32];
    const int tid  = threadIdx.x;
    const int lane = tid & 63, wave = tid >> 6;
    const int lm = lane & 15, quad = lane >> 4;
    const int wr = wave >> 1, wc = wave & 1;

    // T1: XCD-aware block swizzle (all launches have nwg % 8 == 0).
    const int gx = gridDim.x;
    int lin = blockIdx.y * gx + blockIdx.x;
    const int cpx = (gx * gridDim.y) >> 3;
    lin = (lin & 7) * cpx + (lin >> 3);
    const int rowBase = (lin / gx) * 128, colBase = (lin % gx) * (32 * BJ);

    f32x4 acc[4][BJ] = {};

    for (int k0 = 0; k0 < K; k0 += 32) {
        #pragma unroll
        for (int i = 0; i < 2; ++i) {
            int c = tid + 256 * i;
            GLD_LDS16(A  + ((size_t)(rowBase + (c >> 2)) * K + k0 + (c & 3) * 8), &AsU[c * 8]);
        }
        #pragma unroll
        for (int i = 0; i < BJ / 2; ++i) {
            int c = tid + 256 * i;
            GLD_LDS16(WT + ((size_t)(colBase + (c >> 2)) * K + k0 + (c & 3) * 8), &BsU[c * 8]);
        }
        __syncthreads();
        s16x8 a[4], b[BJ];
        #pragma unroll
        for (int i = 0; i < 4; ++i)
            a[i] = *reinterpret_cast<const s16x8*>(&AsU[(wr*64 + i*16 + lm) * 32 + quad*8]);
        #pragma unroll
        for (int j = 0; j < BJ; ++j)
            b[j] = *reinterpret_cast<const s16x8*>(&BsU[(wc*16*BJ + j*16 + lm) * 32 + quad*8]);
        #pragma unroll
        for (int i = 0; i < 4; ++i)
            #pragma unroll
            for (int j = 0; j < BJ; ++j)
                acc[i][j] = __builtin_amdgcn_mfma_f32_16x16x32_bf16(a[i], b[j], acc[i][j], 0, 0, 0);
        __syncthreads();
    }

    #pragma unroll
    for (int j = 0; j < BJ; ++j) {
        const int col = colBase + wc*16*BJ + j*16 + lm;
        const void* bp = b0;
        int bcol = col;
        if (FUSE3) {
            const int sel = col >> 10;
            bp = (sel == 0) ? b0 : ((sel == 1) ? b1 : b2);
            bcol = col & 1023;
        }
        const float bv = ldx(bp, (size_t)bcol, fl);
        #pragma unroll
        for (int i = 0; i < 4; ++i) {
            const int row0 = rowBase + wr*64 + i*16 + quad*4;
            float vv[4];
            #pragma unroll
            for (int r = 0; r < 4; ++r) {
                const int row = row0 + r;
                float v = acc[i][j][r] + bv;
                // fold softmax scale log2(e)/8 into Q (cols 0..1023 of fused
                // QKV). Single fp32 mul before the only bf16 rounding: exact.
                if (FUSE3) { if ((col >> 10) == 0) v *= 0.18033688011112042f; }
                if (RES == 1) v += ldx(res_, (size_t)row * N + col, fl);
                else if (RES == 2) v += bf2f(((const unsigned short*)res_)[(size_t)row * N + col]);
                if (GELU) v = gelu_f(v);
                vv[r] = v;
            }
            #pragma unroll
            for (int rp = 0; rp < 2; ++rp) {
                unsigned int pk;
                asm("v_cvt_pk_bf16_f32 %0, %1, %2"
                    : "=v"(pk) : "v"(vv[2*rp]), "v"(vv[2*rp+1]));
                out[(size_t)(row0 + 2*rp)     * N + col] = (unsigned short)pk;
                out[(size_t)(row0 + 2*rp + 1) * N + col] = (unsigned short)(pk >> 16);
            }
        }
    }
}

// ---------------- MFMA flash attention (r12) --------------------------------
// grid (SEQ/128, B*H), block 512 = 8 waves x 16 Q-rows. K-chunk = 64 keys.
// Fixed-max softmax with log2e/8 pre-folded into Q: p = exp2(s) directly.
// Vt: [64][64] 16B-chunk XOR swizzle (jq ^ (d&7) ^ ((d>>3)&7)) -> scatter
// writes hit all 32 banks (2 lanes/bank same-word = free). Pl: chunk swizzle
// jq ^ (row>>2) -> stores ~2-way. P f32->bf16 via v_cvt_pk_bf16_f32 pairs.
__global__ __launch_bounds__(512)
void attn_mfma(const unsigned short* __restrict__ Q, const unsigned short* __restrict__ Kb,
               const unsigned short* __restrict__ Vb, unsigned short* __restrict__ ctx,
               int ld)
{
    __shared__ unsigned short Ks[4096];     // [ks][key][32] linear (GLD dest)
    __shared__ unsigned short Vt[64 * 64];  // [d][key], swizzled 16B chunks
    __shared__ unsigned short Pl[8 * 1024]; // per-wave [ks][row16][32], swizzled

    const int tid = threadIdx.x;
    const int lane = tid & 63, wave = tid >> 6;
    const int lm = lane & 15, quad = lane >> 4;
    const int q0 = blockIdx.x * 128;
    const int bh = blockIdx.y;
    const int b = bh >> 4, h = bh & 15;
    const size_t base  = ((size_t)b * SEQ) * ld + (size_t)h * 64;
    const size_t cbase = ((size_t)b * SEQ) * D_MODEL + (size_t)h * 64;
    const int pbase = wave * 1024;
    const int qrow = q0 + wave * 16 + lm;

    s16x8 qf[2];
    #pragma unroll
    for (int ks = 0; ks < 2; ++ks)
        qf[ks] = *reinterpret_cast<const s16x8*>(
            Q + base + (size_t)qrow * ld + ks*32 + quad*8);

    f32x4 O[4] = {};
    float lpart[4] = { 0.f, 0.f, 0.f, 0.f };

    for (int j0 = 0; j0 < SEQ; j0 += 64) {
        __syncthreads();   // all waves done reading Ks/Vt before restage
        {   // stage K: one global_load_lds per thread (512 x 16B = 8KB)
            const int c = tid;
            GLD_LDS16(Kb + base + (size_t)(j0 + ((c >> 2) & 63)) * ld
                                + (c >> 8) * 32 + (c & 3) * 8, &Ks[c * 8]);
        }
        {   // stage V transposed, swizzled: 8 shorts per thread
            const int j = tid >> 3, dp = (tid & 7) * 8, jq = tid >> 6;
            s16x8 v = *reinterpret_cast<const s16x8*>(Vb + base + (size_t)(j0 + j) * ld + dp);
            #pragma unroll
            for (int i = 0; i < 8; ++i) {
                const int d = dp + i;
                const int ph = (jq ^ (d & 7) ^ ((d >> 3) & 7)) & 7;
                Vt[d * 64 + ph * 8 + (j & 7)] = (unsigned short)v[i];
            }
        }
        __syncthreads();

        // S = Q K^T (C-layout: row=quad*4+r, col=nt*16+lm)
        f32x4 s[4] = {};
        #pragma unroll
        for (int ks = 0; ks < 2; ++ks) {
            s16x8 bk[4];
            #pragma unroll
            for (int nt = 0; nt < 4; ++nt)
                bk[nt] = *reinterpret_cast<const s16x8*>(&Ks[ks*2048 + (nt*16 + lm)*32 + quad*8]);
            #pragma unroll
            for (int nt = 0; nt < 4; ++nt)
                s[nt] = __builtin_amdgcn_mfma_f32_16x16x32_bf16(qf[ks], bk[nt], s[nt], 0, 0, 0);
        }

        // fixed-max softmax: p = 2^s (scale folded into Q); pack pairs and
        // store to swizzled Pl; accumulate l per lane.
        #pragma unroll
        for (int nt = 0; nt < 4; ++nt) {
            const int jq = (nt & 1) * 2 + (lm >> 3);
            const int ph = (jq ^ quad) & 3;
            const int colp = pbase + (nt >> 1) * 512 + ph * 8 + (lm & 7);
            #pragma unroll
            for (int rp = 0; rp < 2; ++rp) {
                float p0 = __builtin_amdgcn_exp2f(s[nt][2*rp]);
                float p1 = __builtin_amdgcn_exp2f(s[nt][2*rp + 1]);
                lpart[2*rp]     += p0;
                lpart[2*rp + 1] += p1;
                unsigned int pk;
                asm("v_cvt_pk_bf16_f32 %0, %1, %2" : "=v"(pk) : "v"(p0), "v"(p1));
                const int row0 = quad * 4 + 2 * rp;
                Pl[colp + row0 * 32]       = (unsigned short)pk;
                Pl[colp + (row0 + 1) * 32] = (unsigned short)(pk >> 16);
            }
        }
        // same-wave LDS ordering: no barrier needed between P store and read

        // O += P V
        #pragma unroll
        for (int ks = 0; ks < 2; ++ks) {
            s16x8 pa = *reinterpret_cast<const s16x8*>(
                &Pl[pbase + ks*512 + lm*32 + ((quad ^ (lm >> 2)) & 3) * 8]);
            s16x8 vb[4];
            #pragma unroll
            for (int nt = 0; nt < 4; ++nt) {
                const int d = nt*16 + lm;
                const int ph = ((ks*4 + quad) ^ (d & 7) ^ ((d >> 3) & 7)) & 7;
                vb[nt] = *reinterpret_cast<const s16x8*>(&Vt[d * 64 + ph * 8]);
            }
            #pragma unroll
            for (int nt = 0; nt < 4; ++nt)
                O[nt] = __builtin_amdgcn_mfma_f32_16x16x32_bf16(pa, vb[nt], O[nt], 0, 0, 0);
        }
    }

    // epilogue: reduce l across the 16-lane row group once; O /= l; write ctx
    #pragma unroll
    for (int r = 0; r < 4; ++r) {
        float l = lpart[r];
        l += __shfl_xor(l, 1);
        l += __shfl_xor(l, 2);
        l += __shfl_xor(l, 4);
        l += __shfl_xor(l, 8);
        const float linv = 1.0f / l;
        const size_t ob = cbase + (size_t)(q0 + wave*16 + quad*4 + r) * D_MODEL;
        #pragma unroll
        for (int nt = 0; nt < 4; ++nt)
            ctx[ob + nt*16 + lm] = f2bf(O[nt][r] * linv);
    }
}

// ---------------- LayerNorm over rows of 1024 (bf16 in) ---------------------
template<bool OUTF32>
__global__ __launch_bounds__(256)
void ln_k(const unsigned short* __restrict__ X, const void* __restrict__ g,
          const void* __restrict__ b, void* __restrict__ out,
          const int* __restrict__ flagp)
{
    const int fl = *flagp;
    const int row = blockIdx.x, tid = threadIdx.x;
    float x[4];
    load4ws(X, (size_t)row * D_MODEL + tid*4, x);
    float s  = x[0] + x[1] + x[2] + x[3];
    float sq = fmaf(x[0],x[0], fmaf(x[1],x[1], fmaf(x[2],x[2], x[3]*x[3])));
    #pragma unroll
    for (int off = 1; off < 64; off <<= 1) {
        s  += __shfl_xor(s,  off);
        sq += __shfl_xor(sq, off);
    }
    __shared__ float red[8];
    const int wid = tid >> 6;
    if ((tid & 63) == 0) { red[wid] = s; red[4+wid] = sq; }
    __syncthreads();
    s  = red[0] + red[1] + red[2] + red[3];
    sq = red[4] + red[5] + red[6] + red[7];
    const float mean = s * (1.0f/1024.0f);
    const float var  = sq * (1.0f/1024.0f) - mean*mean;
    const float rstd = rsqrtf(var + LN_EPS);
    float gx[4], bx[4];
    load4ext(g, (size_t)tid*4, fl, gx);
    load4ext(b, (size_t)tid*4, fl, bx);
    float y[4];
    #pragma unroll
    for (int j = 0; j < 4; ++j) y[j] = (x[j] - mean) * rstd * gx[j] + bx[j];
    if (OUTF32) {
        float4 o4 = { y[0], y[1], y[2], y[3] };
        *reinterpret_cast<float4*>((float*)out + (size_t)row * D_MODEL + tid*4) = o4;
    } else {
        ushort4 o4 = { f2bf(y[0]), f2bf(y[1]), f2bf(y[2]), f2bf(y[3]) };
        *reinterpret_cast<ushort4*>((unsigned short*)out + (size_t)row * D_MODEL + tid*4) = o4;
    }
}

extern "C" void kernel_launch(void* const* d_in, const int* in_sizes, int n_in,
                              void* d_out, int out_size, void* d_ws, size_t ws_size,
                              hipStream_t stream) {
    const void* X  = d_in[0];
    const void* Wq = d_in[2];  const void* bq  = d_in[3];
    const void* Wk = d_in[4];  const void* bk  = d_in[5];
    const void* Wv = d_in[6];  const void* bv  = d_in[7];
    const void* Wo = d_in[8];  const void* bo  = d_in[9];
    const void* g1 = d_in[10]; const void* b1  = d_in[11];
    const void* W1 = d_in[12]; const void* bf1 = d_in[13];
    const void* W2 = d_in[14]; const void* bf2 = d_in[15];
    const void* g2 = d_in[16]; const void* b2  = d_in[17];

    int* flag = (int*)d_ws;
    unsigned short* base = (unsigned short*)((char*)d_ws + 4096);
    unsigned short* WTq  = base;                   // [1024,1024] } contiguous =
    unsigned short* WTk  = base + 1048576;         // [1024,1024] } WTqkv
    unsigned short* WTv  = base + 2097152;         // [1024,1024] } [3072,1024]
    unsigned short* WTo  = base + 3145728;         // [1024,1024]
    unsigned short* WT1  = base + 4194304;         // [4096,1024]
    unsigned short* WT2  = base + 8388608;         // [1024,4096]
    unsigned short* Xb   = base + 12582912;        // [4096,1024]
    unsigned short* Bqkv = base + 16777216;        // [4096,3072]
    unsigned short* Bctx = base + 29360128;        // [4096,1024]
    unsigned short* AO   = Bqkv;                   // attn_out [4096,1024] reuse
    unsigned short* H    = base + 33554432;        // [4096,4096]

    dim3 blk(256);
    detect3_k<<<1, 64, 0, stream>>>((const unsigned short*)Wq, flag);

    cvtx_k<<<dim3(4096), blk, 0, stream>>>(X, Xb, flag);
    trans_k<<<dim3(16,16), blk, 0, stream>>>(Wq, WTq, 1024, 1024, flag);
    trans_k<<<dim3(16,16), blk, 0, stream>>>(Wk, WTk, 1024, 1024, flag);
    trans_k<<<dim3(16,16), blk, 0, stream>>>(Wv, WTv, 1024, 1024, flag);
    trans_k<<<dim3(16,16), blk, 0, stream>>>(Wo, WTo, 1024, 1024, flag);
    trans_k<<<dim3(64,16), blk, 0, stream>>>(W1, WT1, 1024, 4096, flag);
    trans_k<<<dim3(16,64), blk, 0, stream>>>(W2, WT2, 4096, 1024, flag);

    // fused QKV: [4096,3072] = Xb @ WTqkv^T (768 blocks = 3/CU); Q pre-scaled
    gemm_mfma<0,false,4,true><<<dim3(24,32), blk, 0, stream>>>(
        Xb, WTq, bq, bk, bv, nullptr, Bqkv, MROWS, 3072, 1024, flag);

    // attention on strided QKV (ld=3072); block=512
    attn_mfma<<<dim3(SEQ/128, 32), dim3(512), 0, stream>>>(
        Bqkv, Bqkv + 1024, Bqkv + 2048, Bctx, 3072);

    // Wo proj + residual(X) -> Xb (pre-LN1), 128x64 tiles (512 blocks)
    gemm_mfma<1,false,2,false><<<dim3(16,32), blk, 0, stream>>>(
        Bctx, WTo, bo, nullptr, nullptr, X, Xb, MROWS, 1024, 1024, flag);
    // LN1 -> AO (attn_out; Bqkv reused)
    ln_k<false><<<dim3(4096), blk, 0, stream>>>(Xb, g1, b1, AO, flag);

    // FFN1 + gelu: full [4096,4096] (1024 blocks = 4/CU)
    gemm_mfma<0,true,4,false><<<dim3(32,32), blk, 0, stream>>>(
        AO, WT1, bf1, nullptr, nullptr, nullptr, H, MROWS, 4096, 1024, flag);
    // FFN2 + residual(AO) in-place, 128x64 tiles (512 blocks)
    gemm_mfma<2,false,2,false><<<dim3(16,32), blk, 0, stream>>>(
        H, WT2, bf2, nullptr, nullptr, AO, AO, MROWS, 1024, 4096, flag);

    // final LN -> fp32 d_out
    ln_k<true><<<dim3(4096), blk, 0, stream>>>(AO, g2, b2, d_out, flag);
}

// Round 3
// 456.628 us; speedup vs baseline: 1.0830x; 1.0217x over previous
//
#include <hip/hip_runtime.h>
#include <hip/hip_bf16.h>

// EncoderLayer: B=2,S=2048,D=1024,H=16,dk=dv=64,FF=4096
// r14: FFN2 round. rocprof: FFN2 gemm 83.4us, MfmaUtil 16.4%, VALU 22.7%,
// HBM 9.4%, occ 21.4% -> latency-bound at 8 waves/CU with half-density
// 128x64 tile. Fix: split-K=2 + BJ=4 (tile 128x128, 2x MFMA/K-step/wave,
// half the barriers), f32 partials to dead ws regions (WTq..WT1 / Xb+Bctx),
// combine2_k adds partials + bias + residual -> bf16 AO (~8us, HBM-bound).
// Same f32 accumulation order class -> bit-comparable accuracy.
// r13 (GELU A&S erf, cvt_pk epilogues, T1 XCD swizzle) and r12 attention
// swizzles unchanged.

#define D_MODEL 1024
#define SEQ 2048
#define MROWS 4096
#define LN_EPS 1e-5f

typedef __attribute__((ext_vector_type(8))) short s16x8;
typedef __attribute__((ext_vector_type(4))) float f32x4;

#define GLD_LDS16(g, l) __builtin_amdgcn_global_load_lds( \
    (const __attribute__((address_space(1))) void*)(g), \
    (__attribute__((address_space(3))) void*)(l), 16, 0, 0)

static __device__ __forceinline__ float bf2f(unsigned short u) {
    return __uint_as_float(((unsigned int)u) << 16);
}
static __device__ __forceinline__ unsigned short f2bf(float f) {
    unsigned int u = __float_as_uint(f);
    unsigned int r = (u + 0x7fffu + ((u >> 16) & 1u)) >> 16;
    return (unsigned short)r;
}
static __device__ __forceinline__ float h2f(unsigned short u) {
    union { unsigned short us; _Float16 h; } cv; cv.us = u; return (float)cv.h;
}
static __device__ __forceinline__ float ldx(const void* p, size_t i, int fl) {
    if (fl == 1) return ((const float*)p)[i];
    unsigned short u = ((const unsigned short*)p)[i];
    return (fl == 2) ? h2f(u) : bf2f(u);
}
static __device__ __forceinline__ void load4ext(const void* p, size_t idx, int fl, float o[4]) {
    if (fl == 1) {
        const float4 f = *reinterpret_cast<const float4*>((const float*)p + idx);
        o[0] = f.x; o[1] = f.y; o[2] = f.z; o[3] = f.w;
    } else {
        const ushort4 u = *reinterpret_cast<const ushort4*>((const unsigned short*)p + idx);
        if (fl == 2) { o[0]=h2f(u.x); o[1]=h2f(u.y); o[2]=h2f(u.z); o[3]=h2f(u.w); }
        else         { o[0]=bf2f(u.x); o[1]=bf2f(u.y); o[2]=bf2f(u.z); o[3]=bf2f(u.w); }
    }
}
static __device__ __forceinline__ void load4ws(const unsigned short* p, size_t idx, float o[4]) {
    const ushort4 u = *reinterpret_cast<const ushort4*>(p + idx);
    o[0] = bf2f(u.x); o[1] = bf2f(u.y); o[2] = bf2f(u.z); o[3] = bf2f(u.w);
}

// Fast exact-precision GELU: A&S 7.1.26 erf, |eps| <= 1.5e-7 (<< bf16 ulp).
static __device__ __forceinline__ float gelu_f(float v) {
    const float x  = v * 0.70710678118654752f;
    const float ax = fabsf(x);
    const float t  = __builtin_amdgcn_rcpf(fmaf(0.3275911f, ax, 1.0f));
    const float e  = __builtin_amdgcn_exp2f(-x * x * 1.4426950408889634f);
    float p = fmaf(1.061405429f, t, -1.453152027f);
    p = fmaf(p, t, 1.421413741f);
    p = fmaf(p, t, -0.284496736f);
    p = fmaf(p, t, 0.254829592f);
    p = p * t;
    float er = fmaf(-p, e, 1.0f);          // erf(|x|)
    er = copysignf(er, x);
    return 0.5f * v * (1.0f + er);
}

// ---------- 3-way dtype detector on Wq ------------------------------------
__global__ void detect3_k(const unsigned short* __restrict__ w, int* __restrict__ flag) {
    const int t = threadIdx.x;
    float mbf = 0.f, mf16 = 0.f;
    for (int i = t; i < 512; i += 64) {
        float a = fabsf(bf2f(w[i])); if (!(a < 1e30f)) a = 1e30f; mbf = fmaxf(mbf, a);
        float b = fabsf(h2f(w[i]));  if (!(b < 1e30f)) b = 1e30f; mf16 = fmaxf(mf16, b);
    }
    #pragma unroll
    for (int off = 1; off < 64; off <<= 1) {
        mbf  = fmaxf(mbf,  __shfl_xor(mbf,  off));
        mf16 = fmaxf(mf16, __shfl_xor(mf16, off));
    }
    if (t == 0) {
        int f;
        if (mbf > 0.5f)       f = 1;   // fp32
        else if (mf16 > 0.5f) f = 0;   // bf16
        else                  f = 2;   // fp16
        *flag = f;
    }
}

// ---------- X (ext, [4096x1024]) -> bf16 ws -------------------------------
__global__ __launch_bounds__(256)
void cvtx_k(const void* __restrict__ X, unsigned short* __restrict__ out,
            const int* __restrict__ flagp) {
    const int fl = *flagp;
    const size_t idx = (size_t)blockIdx.x * 1024 + threadIdx.x * 4;
    float v[4];
    load4ext(X, idx, fl, v);
    ushort4 o = { f2bf(v[0]), f2bf(v[1]), f2bf(v[2]), f2bf(v[3]) };
    *reinterpret_cast<ushort4*>(out + idx) = o;
}

// ---------- W [K,N] ext -> WT bf16 [N,K] (64x64 tiles via LDS) -------------
__global__ __launch_bounds__(256)
void trans_k(const void* __restrict__ W, unsigned short* __restrict__ WT,
             int K, int N, const int* __restrict__ flagp) {
    const int fl = *flagp;
    __shared__ float Tf[64][65];
    const int tid = threadIdx.x;
    const int r0 = blockIdx.y * 64, c0 = blockIdx.x * 64;
    #pragma unroll
    for (int it = 0; it < 4; ++it) {
        int rr = (tid >> 4) + it * 16;
        float v[4];
        load4ext(W, (size_t)(r0 + rr) * N + c0 + (tid & 15) * 4, fl, v);
        Tf[rr][(tid & 15) * 4 + 0] = v[0];
        Tf[rr][(tid & 15) * 4 + 1] = v[1];
        Tf[rr][(tid & 15) * 4 + 2] = v[2];
        Tf[rr][(tid & 15) * 4 + 3] = v[3];
    }
    __syncthreads();
    #pragma unroll
    for (int it = 0; it < 4; ++it) {
        int nr = (tid >> 4) + it * 16;
        int kk = (tid & 15) * 4;
        ushort4 o = { f2bf(Tf[kk+0][nr]), f2bf(Tf[kk+1][nr]),
                      f2bf(Tf[kk+2][nr]), f2bf(Tf[kk+3][nr]) };
        *reinterpret_cast<ushort4*>(WT + (size_t)(c0 + nr) * K + r0 + kk) = o;
    }
}

// ---------- MFMA GEMM: out[M,N](bf16 ws) = A[M,K](bf16 ws) @ WT[N,K]^T -----
// K = per-block K extent; LDK = row stride of A and WT. PART: split-K partial
// mode — blockIdx.z selects K-half, f32 partials to (pz0 | p1lo/p1hi).
template<int RES, bool GELU, int BJ, bool FUSE3, bool PART>
__global__ __launch_bounds__(256)
void gemm_mfma(const unsigned short* __restrict__ A,
               const unsigned short* __restrict__ WT,
               const void* __restrict__ b0, const void* __restrict__ b1,
               const void* __restrict__ b2, const void* __restrict__ res_,
               unsigned short* __restrict__ out, int M, int N, int K, int LDK,
               float* __restrict__ pz0, float* __restrict__ p1lo,
               float* __restrict__ p1hi, const int* __restrict__ flagp)
{
    const int fl = *flagp;
    __shared__ unsigned short AsU[128 * 32];
    __shared__ unsigned short BsU[32 * BJ * 32];
    const int tid  = threadIdx.x;
    const int lane = tid & 63, wave = tid >> 6;
    const int lm = lane & 15, quad = lane >> 4;
    const int wr = wave >> 1, wc = wave & 1;

    // T1: XCD-aware block swizzle (all launches have nwg % 8 == 0).
    const int gx = gridDim.x;
    int lin = blockIdx.y * gx + blockIdx.x;
    const int cpx = (gx * gridDim.y) >> 3;
    lin = (lin & 7) * cpx + (lin >> 3);
    const int rowBase = (lin / gx) * 128, colBase = (lin % gx) * (32 * BJ);

    const int kStart = PART ? blockIdx.z * K : 0;

    f32x4 acc[4][BJ] = {};

    for (int k0 = kStart; k0 < kStart + K; k0 += 32) {
        #pragma unroll
        for (int i = 0; i < 2; ++i) {
            int c = tid + 256 * i;
            GLD_LDS16(A  + ((size_t)(rowBase + (c >> 2)) * LDK + k0 + (c & 3) * 8), &AsU[c * 8]);
        }
        #pragma unroll
        for (int i = 0; i < BJ / 2; ++i) {
            int c = tid + 256 * i;
            GLD_LDS16(WT + ((size_t)(colBase + (c >> 2)) * LDK + k0 + (c & 3) * 8), &BsU[c * 8]);
        }
        __syncthreads();
        s16x8 a[4], b[BJ];
        #pragma unroll
        for (int i = 0; i < 4; ++i)
            a[i] = *reinterpret_cast<const s16x8*>(&AsU[(wr*64 + i*16 + lm) * 32 + quad*8]);
        #pragma unroll
        for (int j = 0; j < BJ; ++j)
            b[j] = *reinterpret_cast<const s16x8*>(&BsU[(wc*16*BJ + j*16 + lm) * 32 + quad*8]);
        #pragma unroll
        for (int i = 0; i < 4; ++i)
            #pragma unroll
            for (int j = 0; j < BJ; ++j)
                acc[i][j] = __builtin_amdgcn_mfma_f32_16x16x32_bf16(a[i], b[j], acc[i][j], 0, 0, 0);
        __syncthreads();
    }

    if (PART) {
        // f32 partial store; row blocks never straddle the 2048 boundary.
        float* const lo = blockIdx.z ? p1lo : pz0;
        float* const hi = blockIdx.z ? p1hi : (pz0 + (size_t)2048 * N);
        float* const pp = (rowBase < 2048) ? lo : hi;
        const int rsub = (rowBase < 2048) ? 0 : 2048;
        #pragma unroll
        for (int j = 0; j < BJ; ++j) {
            const int col = colBase + wc*16*BJ + j*16 + lm;
            #pragma unroll
            for (int i = 0; i < 4; ++i) {
                const int row0 = rowBase + wr*64 + i*16 + quad*4 - rsub;
                #pragma unroll
                for (int r = 0; r < 4; ++r)
                    pp[(size_t)(row0 + r) * N + col] = acc[i][j][r];
            }
        }
        return;
    }

    #pragma unroll
    for (int j = 0; j < BJ; ++j) {
        const int col = colBase + wc*16*BJ + j*16 + lm;
        const void* bp = b0;
        int bcol = col;
        if (FUSE3) {
            const int sel = col >> 10;
            bp = (sel == 0) ? b0 : ((sel == 1) ? b1 : b2);
            bcol = col & 1023;
        }
        const float bv = ldx(bp, (size_t)bcol, fl);
        #pragma unroll
        for (int i = 0; i < 4; ++i) {
            const int row0 = rowBase + wr*64 + i*16 + quad*4;
            float vv[4];
            #pragma unroll
            for (int r = 0; r < 4; ++r) {
                const int row = row0 + r;
                float v = acc[i][j][r] + bv;
                // fold softmax scale log2(e)/8 into Q (cols 0..1023 of fused
                // QKV). Single fp32 mul before the only bf16 rounding: exact.
                if (FUSE3) { if ((col >> 10) == 0) v *= 0.18033688011112042f; }
                if (RES == 1) v += ldx(res_, (size_t)row * N + col, fl);
                else if (RES == 2) v += bf2f(((const unsigned short*)res_)[(size_t)row * N + col]);
                if (GELU) v = gelu_f(v);
                vv[r] = v;
            }
            #pragma unroll
            for (int rp = 0; rp < 2; ++rp) {
                unsigned int pk;
                asm("v_cvt_pk_bf16_f32 %0, %1, %2"
                    : "=v"(pk) : "v"(vv[2*rp]), "v"(vv[2*rp+1]));
                out[(size_t)(row0 + 2*rp)     * N + col] = (unsigned short)pk;
                out[(size_t)(row0 + 2*rp + 1) * N + col] = (unsigned short)(pk >> 16);
            }
        }
    }
}

// ---------- split-K combine: AO = P0 + P1 + bias + AO (residual) -----------
__global__ __launch_bounds__(256)
void combine2_k(const float* __restrict__ p0, const float* __restrict__ p1lo,
                const float* __restrict__ p1hi, const void* __restrict__ bias,
                unsigned short* __restrict__ io, const int* __restrict__ flagp)
{
    const int fl = *flagp;
    const int row = blockIdx.x, tid = threadIdx.x;
    const size_t off = (size_t)row * D_MODEL + tid * 4;
    const float4 a = *reinterpret_cast<const float4*>(p0 + off);
    const float* p1 = (row < 2048) ? (p1lo + off)
                                   : (p1hi + off - (size_t)2048 * D_MODEL);
    const float4 c = *reinterpret_cast<const float4*>(p1);
    float bx[4]; load4ext(bias, (size_t)tid * 4, fl, bx);
    float rx[4]; load4ws(io, off, rx);
    float y[4] = { a.x + c.x + bx[0] + rx[0], a.y + c.y + bx[1] + rx[1],
                   a.z + c.z + bx[2] + rx[2], a.w + c.w + bx[3] + rx[3] };
    unsigned int k0, k1;
    asm("v_cvt_pk_bf16_f32 %0, %1, %2" : "=v"(k0) : "v"(y[0]), "v"(y[1]));
    asm("v_cvt_pk_bf16_f32 %0, %1, %2" : "=v"(k1) : "v"(y[2]), "v"(y[3]));
    ushort4 o = { (unsigned short)k0, (unsigned short)(k0 >> 16),
                  (unsigned short)k1, (unsigned short)(k1 >> 16) };
    *reinterpret_cast<ushort4*>(io + off) = o;
}

// ---------------- MFMA flash attention (r12) --------------------------------
// grid (SEQ/128, B*H), block 512 = 8 waves x 16 Q-rows. K-chunk = 64 keys.
// Fixed-max softmax with log2e/8 pre-folded into Q: p = exp2(s) directly.
// Vt: [64][64] 16B-chunk XOR swizzle (jq ^ (d&7) ^ ((d>>3)&7)) -> scatter
// writes hit all 32 banks (2 lanes/bank same-word = free). Pl: chunk swizzle
// jq ^ (row>>2) -> stores ~2-way. P f32->bf16 via v_cvt_pk_bf16_f32 pairs.
__global__ __launch_bounds__(512)
void attn_mfma(const unsigned short* __restrict__ Q, const unsigned short* __restrict__ Kb,
               const unsigned short* __restrict__ Vb, unsigned short* __restrict__ ctx,
               int ld)
{
    __shared__ unsigned short Ks[4096];     // [ks][key][32] linear (GLD dest)
    __shared__ unsigned short Vt[64 * 64];  // [d][key], swizzled 16B chunks
    __shared__ unsigned short Pl[8 * 1024]; // per-wave [ks][row16][32], swizzled

    const int tid = threadIdx.x;
    const int lane = tid & 63, wave = tid >> 6;
    const int lm = lane & 15, quad = lane >> 4;
    const int q0 = blockIdx.x * 128;
    const int bh = blockIdx.y;
    const int b = bh >> 4, h = bh & 15;
    const size_t base  = ((size_t)b * SEQ) * ld + (size_t)h * 64;
    const size_t cbase = ((size_t)b * SEQ) * D_MODEL + (size_t)h * 64;
    const int pbase = wave * 1024;
    const int qrow = q0 + wave * 16 + lm;

    s16x8 qf[2];
    #pragma unroll
    for (int ks = 0; ks < 2; ++ks)
        qf[ks] = *reinterpret_cast<const s16x8*>(
            Q + base + (size_t)qrow * ld + ks*32 + quad*8);

    f32x4 O[4] = {};
    float lpart[4] = { 0.f, 0.f, 0.f, 0.f };

    for (int j0 = 0; j0 < SEQ; j0 += 64) {
        __syncthreads();   // all waves done reading Ks/Vt before restage
        {   // stage K: one global_load_lds per thread (512 x 16B = 8KB)
            const int c = tid;
            GLD_LDS16(Kb + base + (size_t)(j0 + ((c >> 2) & 63)) * ld
                                + (c >> 8) * 32 + (c & 3) * 8, &Ks[c * 8]);
        }
        {   // stage V transposed, swizzled: 8 shorts per thread
            const int j = tid >> 3, dp = (tid & 7) * 8, jq = tid >> 6;
            s16x8 v = *reinterpret_cast<const s16x8*>(Vb + base + (size_t)(j0 + j) * ld + dp);
            #pragma unroll
            for (int i = 0; i < 8; ++i) {
                const int d = dp + i;
                const int ph = (jq ^ (d & 7) ^ ((d >> 3) & 7)) & 7;
                Vt[d * 64 + ph * 8 + (j & 7)] = (unsigned short)v[i];
            }
        }
        __syncthreads();

        // S = Q K^T (C-layout: row=quad*4+r, col=nt*16+lm)
        f32x4 s[4] = {};
        #pragma unroll
        for (int ks = 0; ks < 2; ++ks) {
            s16x8 bk[4];
            #pragma unroll
            for (int nt = 0; nt < 4; ++nt)
                bk[nt] = *reinterpret_cast<const s16x8*>(&Ks[ks*2048 + (nt*16 + lm)*32 + quad*8]);
            #pragma unroll
            for (int nt = 0; nt < 4; ++nt)
                s[nt] = __builtin_amdgcn_mfma_f32_16x16x32_bf16(qf[ks], bk[nt], s[nt], 0, 0, 0);
        }

        // fixed-max softmax: p = 2^s (scale folded into Q); pack pairs and
        // store to swizzled Pl; accumulate l per lane.
        #pragma unroll
        for (int nt = 0; nt < 4; ++nt) {
            const int jq = (nt & 1) * 2 + (lm >> 3);
            const int ph = (jq ^ quad) & 3;
            const int colp = pbase + (nt >> 1) * 512 + ph * 8 + (lm & 7);
            #pragma unroll
            for (int rp = 0; rp < 2; ++rp) {
                float p0 = __builtin_amdgcn_exp2f(s[nt][2*rp]);
                float p1 = __builtin_amdgcn_exp2f(s[nt][2*rp + 1]);
                lpart[2*rp]     += p0;
                lpart[2*rp + 1] += p1;
                unsigned int pk;
                asm("v_cvt_pk_bf16_f32 %0, %1, %2" : "=v"(pk) : "v"(p0), "v"(p1));
                const int row0 = quad * 4 + 2 * rp;
                Pl[colp + row0 * 32]       = (unsigned short)pk;
                Pl[colp + (row0 + 1) * 32] = (unsigned short)(pk >> 16);
            }
        }
        // same-wave LDS ordering: no barrier needed between P store and read

        // O += P V
        #pragma unroll
        for (int ks = 0; ks < 2; ++ks) {
            s16x8 pa = *reinterpret_cast<const s16x8*>(
                &Pl[pbase + ks*512 + lm*32 + ((quad ^ (lm >> 2)) & 3) * 8]);
            s16x8 vb[4];
            #pragma unroll
            for (int nt = 0; nt < 4; ++nt) {
                const int d = nt*16 + lm;
                const int ph = ((ks*4 + quad) ^ (d & 7) ^ ((d >> 3) & 7)) & 7;
                vb[nt] = *reinterpret_cast<const s16x8*>(&Vt[d * 64 + ph * 8]);
            }
            #pragma unroll
            for (int nt = 0; nt < 4; ++nt)
                O[nt] = __builtin_amdgcn_mfma_f32_16x16x32_bf16(pa, vb[nt], O[nt], 0, 0, 0);
        }
    }

    // epilogue: reduce l across the 16-lane row group once; O /= l; write ctx
    #pragma unroll
    for (int r = 0; r < 4; ++r) {
        float l = lpart[r];
        l += __shfl_xor(l, 1);
        l += __shfl_xor(l, 2);
        l += __shfl_xor(l, 4);
        l += __shfl_xor(l, 8);
        const float linv = 1.0f / l;
        const size_t ob = cbase + (size_t)(q0 + wave*16 + quad*4 + r) * D_MODEL;
        #pragma unroll
        for (int nt = 0; nt < 4; ++nt)
            ctx[ob + nt*16 + lm] = f2bf(O[nt][r] * linv);
    }
}

// ---------------- LayerNorm over rows of 1024 (bf16 in) ---------------------
template<bool OUTF32>
__global__ __launch_bounds__(256)
void ln_k(const unsigned short* __restrict__ X, const void* __restrict__ g,
          const void* __restrict__ b, void* __restrict__ out,
          const int* __restrict__ flagp)
{
    const int fl = *flagp;
    const int row = blockIdx.x, tid = threadIdx.x;
    float x[4];
    load4ws(X, (size_t)row * D_MODEL + tid*4, x);
    float s  = x[0] + x[1] + x[2] + x[3];
    float sq = fmaf(x[0],x[0], fmaf(x[1],x[1], fmaf(x[2],x[2], x[3]*x[3])));
    #pragma unroll
    for (int off = 1; off < 64; off <<= 1) {
        s  += __shfl_xor(s,  off);
        sq += __shfl_xor(sq, off);
    }
    __shared__ float red[8];
    const int wid = tid >> 6;
    if ((tid & 63) == 0) { red[wid] = s; red[4+wid] = sq; }
    __syncthreads();
    s  = red[0] + red[1] + red[2] + red[3];
    sq = red[4] + red[5] + red[6] + red[7];
    const float mean = s * (1.0f/1024.0f);
    const float var  = sq * (1.0f/1024.0f) - mean*mean;
    const float rstd = rsqrtf(var + LN_EPS);
    float gx[4], bx[4];
    load4ext(g, (size_t)tid*4, fl, gx);
    load4ext(b, (size_t)tid*4, fl, bx);
    float y[4];
    #pragma unroll
    for (int j = 0; j < 4; ++j) y[j] = (x[j] - mean) * rstd * gx[j] + bx[j];
    if (OUTF32) {
        float4 o4 = { y[0], y[1], y[2], y[3] };
        *reinterpret_cast<float4*>((float*)out + (size_t)row * D_MODEL + tid*4) = o4;
    } else {
        ushort4 o4 = { f2bf(y[0]), f2bf(y[1]), f2bf(y[2]), f2bf(y[3]) };
        *reinterpret_cast<ushort4*>((unsigned short*)out + (size_t)row * D_MODEL + tid*4) = o4;
    }
}

extern "C" void kernel_launch(void* const* d_in, const int* in_sizes, int n_in,
                              void* d_out, int out_size, void* d_ws, size_t ws_size,
                              hipStream_t stream) {
    const void* X  = d_in[0];
    const void* Wq = d_in[2];  const void* bq  = d_in[3];
    const void* Wk = d_in[4];  const void* bk  = d_in[5];
    const void* Wv = d_in[6];  const void* bv  = d_in[7];
    const void* Wo = d_in[8];  const void* bo  = d_in[9];
    const void* g1 = d_in[10]; const void* b1  = d_in[11];
    const void* W1 = d_in[12]; const void* bf1 = d_in[13];
    const void* W2 = d_in[14]; const void* bf2 = d_in[15];
    const void* g2 = d_in[16]; const void* b2  = d_in[17];

    int* flag = (int*)d_ws;
    unsigned short* base = (unsigned short*)((char*)d_ws + 4096);
    unsigned short* WTq  = base;                   // [1024,1024] } contiguous =
    unsigned short* WTk  = base + 1048576;         // [1024,1024] } WTqkv
    unsigned short* WTv  = base + 2097152;         // [1024,1024] } [3072,1024]
    unsigned short* WTo  = base + 3145728;         // [1024,1024]
    unsigned short* WT1  = base + 4194304;         // [4096,1024]
    unsigned short* WT2  = base + 8388608;         // [1024,4096]
    unsigned short* Xb   = base + 12582912;        // [4096,1024]
    unsigned short* Bqkv = base + 16777216;        // [4096,3072]
    unsigned short* Bctx = base + 29360128;        // [4096,1024]
    unsigned short* AO   = Bqkv;                   // attn_out [4096,1024] reuse
    unsigned short* H    = base + 33554432;        // [4096,4096]

    // split-K f32 partials (live only during FFN2; all regions dead by then):
    float* P0   = (float*)base;                    // 16 MB over WTq..WT1
    float* P1lo = (float*)Xb;                      // rows 0..2047
    float* P1hi = (float*)Bctx;                    // rows 2048..4095

    dim3 blk(256);
    detect3_k<<<1, 64, 0, stream>>>((const unsigned short*)Wq, flag);

    cvtx_k<<<dim3(4096), blk, 0, stream>>>(X, Xb, flag);
    trans_k<<<dim3(16,16), blk, 0, stream>>>(Wq, WTq, 1024, 1024, flag);
    trans_k<<<dim3(16,16), blk, 0, stream>>>(Wk, WTk, 1024, 1024, flag);
    trans_k<<<dim3(16,16), blk, 0, stream>>>(Wv, WTv, 1024, 1024, flag);
    trans_k<<<dim3(16,16), blk, 0, stream>>>(Wo, WTo, 1024, 1024, flag);
    trans_k<<<dim3(64,16), blk, 0, stream>>>(W1, WT1, 1024, 4096, flag);
    trans_k<<<dim3(16,64), blk, 0, stream>>>(W2, WT2, 4096, 1024, flag);

    // fused QKV: [4096,3072] = Xb @ WTqkv^T (768 blocks = 3/CU); Q pre-scaled
    gemm_mfma<0,false,4,true,false><<<dim3(24,32), blk, 0, stream>>>(
        Xb, WTq, bq, bk, bv, nullptr, Bqkv, MROWS, 3072, 1024, 1024,
        nullptr, nullptr, nullptr, flag);

    // attention on strided QKV (ld=3072); block=512
    attn_mfma<<<dim3(SEQ/128, 32), dim3(512), 0, stream>>>(
        Bqkv, Bqkv + 1024, Bqkv + 2048, Bctx, 3072);

    // Wo proj + residual(X) -> Xb (pre-LN1), 128x64 tiles (512 blocks)
    gemm_mfma<1,false,2,false,false><<<dim3(16,32), blk, 0, stream>>>(
        Bctx, WTo, bo, nullptr, nullptr, X, Xb, MROWS, 1024, 1024, 1024,
        nullptr, nullptr, nullptr, flag);
    // LN1 -> AO (attn_out; Bqkv reused)
    ln_k<false><<<dim3(4096), blk, 0, stream>>>(Xb, g1, b1, AO, flag);

    // FFN1 + gelu: full [4096,4096] (1024 blocks = 4/CU)
    gemm_mfma<0,true,4,false,false><<<dim3(32,32), blk, 0, stream>>>(
        AO, WT1, bf1, nullptr, nullptr, nullptr, H, MROWS, 4096, 1024, 1024,
        nullptr, nullptr, nullptr, flag);

    // FFN2 split-K=2, 128x128 tiles: grid (8,32,2) = 512 blocks, f32 partials
    gemm_mfma<0,false,4,false,true><<<dim3(8,32,2), blk, 0, stream>>>(
        H, WT2, nullptr, nullptr, nullptr, nullptr, AO, MROWS, 1024, 2048, 4096,
        P0, P1lo, P1hi, flag);
    // combine: AO = P0 + P1 + bf2 + AO (residual), bf16 in place
    combine2_k<<<dim3(4096), blk, 0, stream>>>(P0, P1lo, P1hi, bf2, AO, flag);

    // final LN -> fp32 d_out
    ln_k<true><<<dim3(4096), blk, 0, stream>>>(AO, g2, b2, d_out, flag);
}

// Round 4
// 429.192 us; speedup vs baseline: 1.1522x; 1.0639x over previous
//
#include <hip/hip_runtime.h>
#include <hip/hip_bf16.h>

// EncoderLayer: B=2,S=2048,D=1024,H=16,dk=dv=64,FF=4096
// r15: pipeline round. All big kernels sat at ~420-430 TF -> common cause:
// 2-barrier-per-K-step structure pays full load latency serially each step
// (K=1024 -> 32 steps, no depth). (a) gemm_mfma: double-buffered LDS,
// stage(t+1) issued BEFORE compute(t), ONE barrier/step -> vmcnt(0) drain
// lands after MFMAs (T3-minimum, m248v2 pattern). (b) attn: 4-wave blocks,
// 32 Q-rows/wave (bk/vb fragment reads shared by 2 row-tiles -> per-CU LDS
// reads 288->160KB/chunk), dbuf Ks/Vt, V loads early + ds_writes late (T14),
// one barrier/chunk. Swizzles (r12) copied verbatim. FFN2 split-K=2 kept.

#define D_MODEL 1024
#define SEQ 2048
#define MROWS 4096
#define LN_EPS 1e-5f

typedef __attribute__((ext_vector_type(8))) short s16x8;
typedef __attribute__((ext_vector_type(4))) float f32x4;

#define GLD_LDS16(g, l) __builtin_amdgcn_global_load_lds( \
    (const __attribute__((address_space(1))) void*)(g), \
    (__attribute__((address_space(3))) void*)(l), 16, 0, 0)

static __device__ __forceinline__ float bf2f(unsigned short u) {
    return __uint_as_float(((unsigned int)u) << 16);
}
static __device__ __forceinline__ unsigned short f2bf(float f) {
    unsigned int u = __float_as_uint(f);
    unsigned int r = (u + 0x7fffu + ((u >> 16) & 1u)) >> 16;
    return (unsigned short)r;
}
static __device__ __forceinline__ float h2f(unsigned short u) {
    union { unsigned short us; _Float16 h; } cv; cv.us = u; return (float)cv.h;
}
static __device__ __forceinline__ float ldx(const void* p, size_t i, int fl) {
    if (fl == 1) return ((const float*)p)[i];
    unsigned short u = ((const unsigned short*)p)[i];
    return (fl == 2) ? h2f(u) : bf2f(u);
}
static __device__ __forceinline__ void load4ext(const void* p, size_t idx, int fl, float o[4]) {
    if (fl == 1) {
        const float4 f = *reinterpret_cast<const float4*>((const float*)p + idx);
        o[0] = f.x; o[1] = f.y; o[2] = f.z; o[3] = f.w;
    } else {
        const ushort4 u = *reinterpret_cast<const ushort4*>((const unsigned short*)p + idx);
        if (fl == 2) { o[0]=h2f(u.x); o[1]=h2f(u.y); o[2]=h2f(u.z); o[3]=h2f(u.w); }
        else         { o[0]=bf2f(u.x); o[1]=bf2f(u.y); o[2]=bf2f(u.z); o[3]=bf2f(u.w); }
    }
}
static __device__ __forceinline__ void load4ws(const unsigned short* p, size_t idx, float o[4]) {
    const ushort4 u = *reinterpret_cast<const ushort4*>(p + idx);
    o[0] = bf2f(u.x); o[1] = bf2f(u.y); o[2] = bf2f(u.z); o[3] = bf2f(u.w);
}

// Fast exact-precision GELU: A&S 7.1.26 erf, |eps| <= 1.5e-7 (<< bf16 ulp).
static __device__ __forceinline__ float gelu_f(float v) {
    const float x  = v * 0.70710678118654752f;
    const float ax = fabsf(x);
    const float t  = __builtin_amdgcn_rcpf(fmaf(0.3275911f, ax, 1.0f));
    const float e  = __builtin_amdgcn_exp2f(-x * x * 1.4426950408889634f);
    float p = fmaf(1.061405429f, t, -1.453152027f);
    p = fmaf(p, t, 1.421413741f);
    p = fmaf(p, t, -0.284496736f);
    p = fmaf(p, t, 0.254829592f);
    p = p * t;
    float er = fmaf(-p, e, 1.0f);          // erf(|x|)
    er = copysignf(er, x);
    return 0.5f * v * (1.0f + er);
}

// ---------- 3-way dtype detector on Wq ------------------------------------
__global__ void detect3_k(const unsigned short* __restrict__ w, int* __restrict__ flag) {
    const int t = threadIdx.x;
    float mbf = 0.f, mf16 = 0.f;
    for (int i = t; i < 512; i += 64) {
        float a = fabsf(bf2f(w[i])); if (!(a < 1e30f)) a = 1e30f; mbf = fmaxf(mbf, a);
        float b = fabsf(h2f(w[i]));  if (!(b < 1e30f)) b = 1e30f; mf16 = fmaxf(mf16, b);
    }
    #pragma unroll
    for (int off = 1; off < 64; off <<= 1) {
        mbf  = fmaxf(mbf,  __shfl_xor(mbf,  off));
        mf16 = fmaxf(mf16, __shfl_xor(mf16, off));
    }
    if (t == 0) {
        int f;
        if (mbf > 0.5f)       f = 1;   // fp32
        else if (mf16 > 0.5f) f = 0;   // bf16
        else                  f = 2;   // fp16
        *flag = f;
    }
}

// ---------- X (ext, [4096x1024]) -> bf16 ws -------------------------------
__global__ __launch_bounds__(256)
void cvtx_k(const void* __restrict__ X, unsigned short* __restrict__ out,
            const int* __restrict__ flagp) {
    const int fl = *flagp;
    const size_t idx = (size_t)blockIdx.x * 1024 + threadIdx.x * 4;
    float v[4];
    load4ext(X, idx, fl, v);
    ushort4 o = { f2bf(v[0]), f2bf(v[1]), f2bf(v[2]), f2bf(v[3]) };
    *reinterpret_cast<ushort4*>(out + idx) = o;
}

// ---------- W [K,N] ext -> WT bf16 [N,K] (64x64 tiles via LDS) -------------
__global__ __launch_bounds__(256)
void trans_k(const void* __restrict__ W, unsigned short* __restrict__ WT,
             int K, int N, const int* __restrict__ flagp) {
    const int fl = *flagp;
    __shared__ float Tf[64][65];
    const int tid = threadIdx.x;
    const int r0 = blockIdx.y * 64, c0 = blockIdx.x * 64;
    #pragma unroll
    for (int it = 0; it < 4; ++it) {
        int rr = (tid >> 4) + it * 16;
        float v[4];
        load4ext(W, (size_t)(r0 + rr) * N + c0 + (tid & 15) * 4, fl, v);
        Tf[rr][(tid & 15) * 4 + 0] = v[0];
        Tf[rr][(tid & 15) * 4 + 1] = v[1];
        Tf[rr][(tid & 15) * 4 + 2] = v[2];
        Tf[rr][(tid & 15) * 4 + 3] = v[3];
    }
    __syncthreads();
    #pragma unroll
    for (int it = 0; it < 4; ++it) {
        int nr = (tid >> 4) + it * 16;
        int kk = (tid & 15) * 4;
        ushort4 o = { f2bf(Tf[kk+0][nr]), f2bf(Tf[kk+1][nr]),
                      f2bf(Tf[kk+2][nr]), f2bf(Tf[kk+3][nr]) };
        *reinterpret_cast<ushort4*>(WT + (size_t)(c0 + nr) * K + r0 + kk) = o;
    }
}

// ---------- MFMA GEMM: out[M,N](bf16 ws) = A[M,K](bf16 ws) @ WT[N,K]^T -----
// Double-buffered LDS, stage-ahead, one barrier per K-step. K = per-block K
// extent; LDK = row stride. PART: split-K partial mode (f32 partials).
template<int RES, bool GELU, int BJ, bool FUSE3, bool PART>
__global__ __launch_bounds__(256)
void gemm_mfma(const unsigned short* __restrict__ A,
               const unsigned short* __restrict__ WT,
               const void* __restrict__ b0, const void* __restrict__ b1,
               const void* __restrict__ b2, const void* __restrict__ res_,
               unsigned short* __restrict__ out, int M, int N, int K, int LDK,
               float* __restrict__ pz0, float* __restrict__ p1lo,
               float* __restrict__ p1hi, const int* __restrict__ flagp)
{
    const int fl = *flagp;
    __shared__ unsigned short AsU[2][128 * 32];
    __shared__ unsigned short BsU[2][32 * BJ * 32];
    const int tid  = threadIdx.x;
    const int lane = tid & 63, wave = tid >> 6;
    const int lm = lane & 15, quad = lane >> 4;
    const int wr = wave >> 1, wc = wave & 1;

    // T1: XCD-aware block swizzle (all launches have nwg % 8 == 0).
    const int gx = gridDim.x;
    int lin = blockIdx.y * gx + blockIdx.x;
    const int cpx = (gx * gridDim.y) >> 3;
    lin = (lin & 7) * cpx + (lin >> 3);
    const int rowBase = (lin / gx) * 128, colBase = (lin % gx) * (32 * BJ);

    const int kStart = PART ? blockIdx.z * K : 0;
    const int NT = K >> 5;

    auto stage = [&](int k0, int buf) {
        #pragma unroll
        for (int i = 0; i < 2; ++i) {
            int c = tid + 256 * i;
            GLD_LDS16(A  + ((size_t)(rowBase + (c >> 2)) * LDK + k0 + (c & 3) * 8),
                      &AsU[buf][c * 8]);
        }
        #pragma unroll
        for (int i = 0; i < BJ / 2; ++i) {
            int c = tid + 256 * i;
            GLD_LDS16(WT + ((size_t)(colBase + (c >> 2)) * LDK + k0 + (c & 3) * 8),
                      &BsU[buf][c * 8]);
        }
    };

    stage(kStart, 0);
    __syncthreads();

    f32x4 acc[4][BJ] = {};

    for (int t = 0; t < NT; ++t) {
        const int cur = t & 1;
        const bool more = (t + 1 < NT);
        if (more) stage(kStart + (t + 1) * 32, cur ^ 1);
        s16x8 a[4], b[BJ];
        #pragma unroll
        for (int i = 0; i < 4; ++i)
            a[i] = *reinterpret_cast<const s16x8*>(&AsU[cur][(wr*64 + i*16 + lm) * 32 + quad*8]);
        #pragma unroll
        for (int j = 0; j < BJ; ++j)
            b[j] = *reinterpret_cast<const s16x8*>(&BsU[cur][(wc*16*BJ + j*16 + lm) * 32 + quad*8]);
        #pragma unroll
        for (int i = 0; i < 4; ++i)
            #pragma unroll
            for (int j = 0; j < BJ; ++j)
                acc[i][j] = __builtin_amdgcn_mfma_f32_16x16x32_bf16(a[i], b[j], acc[i][j], 0, 0, 0);
        if (more) __syncthreads();
    }

    if (PART) {
        // f32 partial store; row blocks never straddle the 2048 boundary.
        float* const lo = blockIdx.z ? p1lo : pz0;
        float* const hi = blockIdx.z ? p1hi : (pz0 + (size_t)2048 * N);
        float* const pp = (rowBase < 2048) ? lo : hi;
        const int rsub = (rowBase < 2048) ? 0 : 2048;
        #pragma unroll
        for (int j = 0; j < BJ; ++j) {
            const int col = colBase + wc*16*BJ + j*16 + lm;
            #pragma unroll
            for (int i = 0; i < 4; ++i) {
                const int row0 = rowBase + wr*64 + i*16 + quad*4 - rsub;
                #pragma unroll
                for (int r = 0; r < 4; ++r)
                    pp[(size_t)(row0 + r) * N + col] = acc[i][j][r];
            }
        }
        return;
    }

    #pragma unroll
    for (int j = 0; j < BJ; ++j) {
        const int col = colBase + wc*16*BJ + j*16 + lm;
        const void* bp = b0;
        int bcol = col;
        if (FUSE3) {
            const int sel = col >> 10;
            bp = (sel == 0) ? b0 : ((sel == 1) ? b1 : b2);
            bcol = col & 1023;
        }
        const float bv = ldx(bp, (size_t)bcol, fl);
        #pragma unroll
        for (int i = 0; i < 4; ++i) {
            const int row0 = rowBase + wr*64 + i*16 + quad*4;
            float vv[4];
            #pragma unroll
            for (int r = 0; r < 4; ++r) {
                const int row = row0 + r;
                float v = acc[i][j][r] + bv;
                // fold softmax scale log2(e)/8 into Q (cols 0..1023 of fused
                // QKV). Single fp32 mul before the only bf16 rounding: exact.
                if (FUSE3) { if ((col >> 10) == 0) v *= 0.18033688011112042f; }
                if (RES == 1) v += ldx(res_, (size_t)row * N + col, fl);
                else if (RES == 2) v += bf2f(((const unsigned short*)res_)[(size_t)row * N + col]);
                if (GELU) v = gelu_f(v);
                vv[r] = v;
            }
            #pragma unroll
            for (int rp = 0; rp < 2; ++rp) {
                unsigned int pk;
                asm("v_cvt_pk_bf16_f32 %0, %1, %2"
                    : "=v"(pk) : "v"(vv[2*rp]), "v"(vv[2*rp+1]));
                out[(size_t)(row0 + 2*rp)     * N + col] = (unsigned short)pk;
                out[(size_t)(row0 + 2*rp + 1) * N + col] = (unsigned short)(pk >> 16);
            }
        }
    }
}

// ---------- split-K combine: AO = P0 + P1 + bias + AO (residual) -----------
__global__ __launch_bounds__(256)
void combine2_k(const float* __restrict__ p0, const float* __restrict__ p1lo,
                const float* __restrict__ p1hi, const void* __restrict__ bias,
                unsigned short* __restrict__ io, const int* __restrict__ flagp)
{
    const int fl = *flagp;
    const int row = blockIdx.x, tid = threadIdx.x;
    const size_t off = (size_t)row * D_MODEL + tid * 4;
    const float4 a = *reinterpret_cast<const float4*>(p0 + off);
    const float* p1 = (row < 2048) ? (p1lo + off)
                                   : (p1hi + off - (size_t)2048 * D_MODEL);
    const float4 c = *reinterpret_cast<const float4*>(p1);
    float bx[4]; load4ext(bias, (size_t)tid * 4, fl, bx);
    float rx[4]; load4ws(io, off, rx);
    float y[4] = { a.x + c.x + bx[0] + rx[0], a.y + c.y + bx[1] + rx[1],
                   a.z + c.z + bx[2] + rx[2], a.w + c.w + bx[3] + rx[3] };
    unsigned int k0, k1;
    asm("v_cvt_pk_bf16_f32 %0, %1, %2" : "=v"(k0) : "v"(y[0]), "v"(y[1]));
    asm("v_cvt_pk_bf16_f32 %0, %1, %2" : "=v"(k1) : "v"(y[2]), "v"(y[3]));
    ushort4 o = { (unsigned short)k0, (unsigned short)(k0 >> 16),
                  (unsigned short)k1, (unsigned short)(k1 >> 16) };
    *reinterpret_cast<ushort4*>(io + off) = o;
}

// ---------------- MFMA flash attention (r15) --------------------------------
// grid (SEQ/128, B*H), block 256 = 4 waves x 32 Q-rows (2 row-tiles of 16).
// K-chunk = 64 keys, double-buffered Ks/Vt, ONE barrier per chunk:
// stage(t+1) issued before compute(t); V ds_writes after compute (T14).
// bk/vb fragment reads serve BOTH row-tiles (halves per-CU LDS read traffic).
// Fixed-max softmax, scale log2e/8 pre-folded into Q. Swizzles as r12.
__global__ __launch_bounds__(256, 2)
void attn_mfma(const unsigned short* __restrict__ Q, const unsigned short* __restrict__ Kb,
               const unsigned short* __restrict__ Vb, unsigned short* __restrict__ ctx,
               int ld)
{
    __shared__ unsigned short Ks[2][4096];  // [ks][key][32] linear (GLD dest)
    __shared__ unsigned short Vt[2][4096];  // [d][key], swizzled 16B chunks
    __shared__ unsigned short Pl[8192];     // per (wave,rt) [ks][row16][32], swizzled

    const int tid = threadIdx.x;
    const int lane = tid & 63, wave = tid >> 6;
    const int lm = lane & 15, quad = lane >> 4;
    const int q0 = blockIdx.x * 128;
    const int bh = blockIdx.y;
    const int b = bh >> 4, h = bh & 15;
    const size_t base  = ((size_t)b * SEQ) * ld + (size_t)h * 64;
    const size_t cbase = ((size_t)b * SEQ) * D_MODEL + (size_t)h * 64;

    s16x8 qf[2][2];
    #pragma unroll
    for (int rt = 0; rt < 2; ++rt)
        #pragma unroll
        for (int ks = 0; ks < 2; ++ks)
            qf[rt][ks] = *reinterpret_cast<const s16x8*>(
                Q + base + (size_t)(q0 + wave*32 + rt*16 + lm) * ld + ks*32 + quad*8);

    f32x4 O[2][4] = {};
    float lpart[2][4] = {};
    s16x8 vr[2];

    auto stageK = [&](int j0, int buf) {
        #pragma unroll
        for (int i = 0; i < 2; ++i) {
            const int c = tid + 256 * i;
            GLD_LDS16(Kb + base + (size_t)(j0 + ((c >> 2) & 63)) * ld
                                + (c >> 8) * 32 + (c & 3) * 8, &Ks[buf][c * 8]);
        }
    };
    auto loadV = [&](int j0) {
        #pragma unroll
        for (int i = 0; i < 2; ++i) {
            const int t2 = tid + 256 * i;
            vr[i] = *reinterpret_cast<const s16x8*>(
                Vb + base + (size_t)(j0 + (t2 >> 3)) * ld + (t2 & 7) * 8);
        }
    };
    auto writeVt = [&](int buf) {
        #pragma unroll
        for (int i2 = 0; i2 < 2; ++i2) {
            const int t2 = tid + 256 * i2;
            const int j = t2 >> 3, dp = (t2 & 7) * 8, jq = t2 >> 6;
            #pragma unroll
            for (int i = 0; i < 8; ++i) {
                const int d = dp + i;
                const int ph = (jq ^ (d & 7) ^ ((d >> 3) & 7)) & 7;
                Vt[buf][d * 64 + ph * 8 + (j & 7)] = (unsigned short)vr[i2][i];
            }
        }
    };

    // prologue: stage chunk 0 into buffer 0
    stageK(0, 0);
    loadV(0);
    writeVt(0);
    __syncthreads();

    for (int ci = 0; ci < SEQ / 64; ++ci) {
        const int cur = ci & 1;
        const bool more = (ci + 1 < SEQ / 64);
        if (more) { stageK((ci + 1) * 64, cur ^ 1); loadV((ci + 1) * 64); }

        // S = Q K^T; bk fragments shared by both row-tiles
        s16x8 bk[2][4];
        #pragma unroll
        for (int ks = 0; ks < 2; ++ks)
            #pragma unroll
            for (int nt = 0; nt < 4; ++nt)
                bk[ks][nt] = *reinterpret_cast<const s16x8*>(
                    &Ks[cur][ks*2048 + (nt*16 + lm)*32 + quad*8]);
        f32x4 s[2][4] = {};
        #pragma unroll
        for (int rt = 0; rt < 2; ++rt)
            #pragma unroll
            for (int ks = 0; ks < 2; ++ks)
                #pragma unroll
                for (int nt = 0; nt < 4; ++nt)
                    s[rt][nt] = __builtin_amdgcn_mfma_f32_16x16x32_bf16(
                        qf[rt][ks], bk[ks][nt], s[rt][nt], 0, 0, 0);

        // fixed-max softmax: p = 2^s; pack pairs to swizzled Pl; accumulate l
        #pragma unroll
        for (int rt = 0; rt < 2; ++rt) {
            const int pbase = (wave * 2 + rt) * 1024;
            #pragma unroll
            for (int nt = 0; nt < 4; ++nt) {
                const int jq = (nt & 1) * 2 + (lm >> 3);
                const int ph = (jq ^ quad) & 3;
                const int colp = pbase + (nt >> 1) * 512 + ph * 8 + (lm & 7);
                #pragma unroll
                for (int rp = 0; rp < 2; ++rp) {
                    float p0 = __builtin_amdgcn_exp2f(s[rt][nt][2*rp]);
                    float p1 = __builtin_amdgcn_exp2f(s[rt][nt][2*rp + 1]);
                    lpart[rt][2*rp]     += p0;
                    lpart[rt][2*rp + 1] += p1;
                    unsigned int pk;
                    asm("v_cvt_pk_bf16_f32 %0, %1, %2" : "=v"(pk) : "v"(p0), "v"(p1));
                    const int row0 = quad * 4 + 2 * rp;
                    Pl[colp + row0 * 32]       = (unsigned short)pk;
                    Pl[colp + (row0 + 1) * 32] = (unsigned short)(pk >> 16);
                }
            }
        }
        // same-wave LDS ordering: no barrier between P store and read

        // O += P V; vb fragments shared by both row-tiles
        #pragma unroll
        for (int ks = 0; ks < 2; ++ks) {
            s16x8 vb[4];
            #pragma unroll
            for (int nt = 0; nt < 4; ++nt) {
                const int d = nt*16 + lm;
                const int ph = ((ks*4 + quad) ^ (d & 7) ^ ((d >> 3) & 7)) & 7;
                vb[nt] = *reinterpret_cast<const s16x8*>(&Vt[cur][d * 64 + ph * 8]);
            }
            #pragma unroll
            for (int rt = 0; rt < 2; ++rt) {
                const s16x8 pa = *reinterpret_cast<const s16x8*>(
                    &Pl[(wave*2 + rt)*1024 + ks*512 + lm*32 + ((quad ^ (lm >> 2)) & 3) * 8]);
                #pragma unroll
                for (int nt = 0; nt < 4; ++nt)
                    O[rt][nt] = __builtin_amdgcn_mfma_f32_16x16x32_bf16(
                        pa, vb[nt], O[rt][nt], 0, 0, 0);
            }
        }

        if (more) { writeVt(cur ^ 1); __syncthreads(); }
    }

    // epilogue: reduce l across the 16-lane row group; O /= l; write ctx
    #pragma unroll
    for (int rt = 0; rt < 2; ++rt)
        #pragma unroll
        for (int r = 0; r < 4; ++r) {
            float l = lpart[rt][r];
            l += __shfl_xor(l, 1);
            l += __shfl_xor(l, 2);
            l += __shfl_xor(l, 4);
            l += __shfl_xor(l, 8);
            const float linv = 1.0f / l;
            const size_t ob = cbase + (size_t)(q0 + wave*32 + rt*16 + quad*4 + r) * D_MODEL;
            #pragma unroll
            for (int nt = 0; nt < 4; ++nt)
                ctx[ob + nt*16 + lm] = f2bf(O[rt][nt][r] * linv);
        }
}

// ---------------- LayerNorm over rows of 1024 (bf16 in) ---------------------
template<bool OUTF32>
__global__ __launch_bounds__(256)
void ln_k(const unsigned short* __restrict__ X, const void* __restrict__ g,
          const void* __restrict__ b, void* __restrict__ out,
          const int* __restrict__ flagp)
{
    const int fl = *flagp;
    const int row = blockIdx.x, tid = threadIdx.x;
    float x[4];
    load4ws(X, (size_t)row * D_MODEL + tid*4, x);
    float s  = x[0] + x[1] + x[2] + x[3];
    float sq = fmaf(x[0],x[0], fmaf(x[1],x[1], fmaf(x[2],x[2], x[3]*x[3])));
    #pragma unroll
    for (int off = 1; off < 64; off <<= 1) {
        s  += __shfl_xor(s,  off);
        sq += __shfl_xor(sq, off);
    }
    __shared__ float red[8];
    const int wid = tid >> 6;
    if ((tid & 63) == 0) { red[wid] = s; red[4+wid] = sq; }
    __syncthreads();
    s  = red[0] + red[1] + red[2] + red[3];
    sq = red[4] + red[5] + red[6] + red[7];
    const float mean = s * (1.0f/1024.0f);
    const float var  = sq * (1.0f/1024.0f) - mean*mean;
    const float rstd = rsqrtf(var + LN_EPS);
    float gx[4], bx[4];
    load4ext(g, (size_t)tid*4, fl, gx);
    load4ext(b, (size_t)tid*4, fl, bx);
    float y[4];
    #pragma unroll
    for (int j = 0; j < 4; ++j) y[j] = (x[j] - mean) * rstd * gx[j] + bx[j];
    if (OUTF32) {
        float4 o4 = { y[0], y[1], y[2], y[3] };
        *reinterpret_cast<float4*>((float*)out + (size_t)row * D_MODEL + tid*4) = o4;
    } else {
        ushort4 o4 = { f2bf(y[0]), f2bf(y[1]), f2bf(y[2]), f2bf(y[3]) };
        *reinterpret_cast<ushort4*>((unsigned short*)out + (size_t)row * D_MODEL + tid*4) = o4;
    }
}

extern "C" void kernel_launch(void* const* d_in, const int* in_sizes, int n_in,
                              void* d_out, int out_size, void* d_ws, size_t ws_size,
                              hipStream_t stream) {
    const void* X  = d_in[0];
    const void* Wq = d_in[2];  const void* bq  = d_in[3];
    const void* Wk = d_in[4];  const void* bk  = d_in[5];
    const void* Wv = d_in[6];  const void* bv  = d_in[7];
    const void* Wo = d_in[8];  const void* bo  = d_in[9];
    const void* g1 = d_in[10]; const void* b1  = d_in[11];
    const void* W1 = d_in[12]; const void* bf1 = d_in[13];
    const void* W2 = d_in[14]; const void* bf2 = d_in[15];
    const void* g2 = d_in[16]; const void* b2  = d_in[17];

    int* flag = (int*)d_ws;
    unsigned short* base = (unsigned short*)((char*)d_ws + 4096);
    unsigned short* WTq  = base;                   // [1024,1024] } contiguous =
    unsigned short* WTk  = base + 1048576;         // [1024,1024] } WTqkv
    unsigned short* WTv  = base + 2097152;         // [1024,1024] } [3072,1024]
    unsigned short* WTo  = base + 3145728;         // [1024,1024]
    unsigned short* WT1  = base + 4194304;         // [4096,1024]
    unsigned short* WT2  = base + 8388608;         // [1024,4096]
    unsigned short* Xb   = base + 12582912;        // [4096,1024]
    unsigned short* Bqkv = base + 16777216;        // [4096,3072]
    unsigned short* Bctx = base + 29360128;        // [4096,1024]
    unsigned short* AO   = Bqkv;                   // attn_out [4096,1024] reuse
    unsigned short* H    = base + 33554432;        // [4096,4096]

    // split-K f32 partials (live only during FFN2; all regions dead by then):
    float* P0   = (float*)base;                    // 16 MB over WTq..WT1
    float* P1lo = (float*)Xb;                      // rows 0..2047
    float* P1hi = (float*)Bctx;                    // rows 2048..4095

    dim3 blk(256);
    detect3_k<<<1, 64, 0, stream>>>((const unsigned short*)Wq, flag);

    cvtx_k<<<dim3(4096), blk, 0, stream>>>(X, Xb, flag);
    trans_k<<<dim3(16,16), blk, 0, stream>>>(Wq, WTq, 1024, 1024, flag);
    trans_k<<<dim3(16,16), blk, 0, stream>>>(Wk, WTk, 1024, 1024, flag);
    trans_k<<<dim3(16,16), blk, 0, stream>>>(Wv, WTv, 1024, 1024, flag);
    trans_k<<<dim3(16,16), blk, 0, stream>>>(Wo, WTo, 1024, 1024, flag);
    trans_k<<<dim3(64,16), blk, 0, stream>>>(W1, WT1, 1024, 4096, flag);
    trans_k<<<dim3(16,64), blk, 0, stream>>>(W2, WT2, 4096, 1024, flag);

    // fused QKV: [4096,3072] = Xb @ WTqkv^T (768 blocks = 3/CU); Q pre-scaled
    gemm_mfma<0,false,4,true,false><<<dim3(24,32), blk, 0, stream>>>(
        Xb, WTq, bq, bk, bv, nullptr, Bqkv, MROWS, 3072, 1024, 1024,
        nullptr, nullptr, nullptr, flag);

    // attention on strided QKV (ld=3072); block=256, 4 waves x 32 rows
    attn_mfma<<<dim3(SEQ/128, 32), dim3(256), 0, stream>>>(
        Bqkv, Bqkv + 1024, Bqkv + 2048, Bctx, 3072);

    // Wo proj + residual(X) -> Xb (pre-LN1), 128x64 tiles (512 blocks)
    gemm_mfma<1,false,2,false,false><<<dim3(16,32), blk, 0, stream>>>(
        Bctx, WTo, bo, nullptr, nullptr, X, Xb, MROWS, 1024, 1024, 1024,
        nullptr, nullptr, nullptr, flag);
    // LN1 -> AO (attn_out; Bqkv reused)
    ln_k<false><<<dim3(4096), blk, 0, stream>>>(Xb, g1, b1, AO, flag);

    // FFN1 + gelu: full [4096,4096] (1024 blocks = 4/CU)
    gemm_mfma<0,true,4,false,false><<<dim3(32,32), blk, 0, stream>>>(
        AO, WT1, bf1, nullptr, nullptr, nullptr, H, MROWS, 4096, 1024, 1024,
        nullptr, nullptr, nullptr, flag);

    // FFN2 split-K=2, 128x128 tiles: grid (8,32,2) = 512 blocks, f32 partials
    gemm_mfma<0,false,4,false,true><<<dim3(8,32,2), blk, 0, stream>>>(
        H, WT2, nullptr, nullptr, nullptr, nullptr, AO, MROWS, 1024, 2048, 4096,
        P0, P1lo, P1hi, flag);
    // combine: AO = P0 + P1 + bf2 + AO (residual), bf16 in place
    combine2_k<<<dim3(4096), blk, 0, stream>>>(P0, P1lo, P1hi, bf2, AO, flag);

    // final LN -> fp32 d_out
    ln_k<true><<<dim3(4096), blk, 0, stream>>>(AO, g2, b2, d_out, flag);
}